// Round 13
// baseline (491.239 us; speedup 1.0000x reference)
//
#include <hip/hip_runtime.h>
#include <hip/hip_fp16.h>

#define B_    16
#define C_    256
#define HW_   4096
#define CHW_  1048576
#define N_    65536
#define K_    1024
#define FLT_BIG 3.402823466e38f
#define GAP_T  1.2e-4f   // ref fp32-quant floor 6.1e-5 + 6sigma fp16 score err ~3.1e-5 + key-pack 8e-6 + margin

typedef _Float16 half8 __attribute__((ext_vector_type(8)));
typedef float   float16 __attribute__((ext_vector_type(16)));

__device__ __forceinline__ unsigned umin_(unsigned a, unsigned b) { return a < b ? a : b; }
__device__ __forceinline__ unsigned umax_(unsigned a, unsigned b) { return a > b ? a : b; }

// ---------------------------------------------------------------------------
// s_z split into 16x-parallel partial pass + exact combine (PASSED r7).
// ---------------------------------------------------------------------------
__global__ void szp_kernel(const float* __restrict__ z, float* __restrict__ rp) {
#pragma clang fp contract(off)
    int hj = blockIdx.x >> 8;              // 0..15  (h = hj>>3, j = hj&7)
    int bx = blockIdx.x & 255;
    int n  = bx * 256 + threadIdx.x;
    int h = hj >> 3, j = hj & 7;
    const float* p = z + (size_t)(n >> 12) * CHW_ + (n & 4095)
                       + (size_t)(h * 128 + j) * HW_;
    float v = p[0];
    float r = v * v;
    for (int s = 1; s < 16; s++) {
        float u = p[(size_t)(s * 8) * HW_];
        r += u * u;
    }
    rp[(size_t)hj * N_ + n] = r;
}

__global__ void szc_kernel(const float* __restrict__ rp, float* __restrict__ sz) {
#pragma clang fp contract(off)
    int n = blockIdx.x * 256 + threadIdx.x;
    float blk[2];
    for (int h = 0; h < 2; h++) {
        const float* b = rp + (size_t)(h * 8) * N_ + n;
        float r0 = b[0 * N_], r1 = b[1 * N_], r2 = b[2 * N_], r3 = b[3 * N_];
        float r4 = b[4 * N_], r5 = b[5 * N_], r6 = b[6 * N_], r7 = b[7 * N_];
        blk[h] = ((r0 + r1) + (r2 + r3)) + ((r4 + r5) + (r6 + r7));
    }
    sz[n] = blk[0] + blk[1];
}

// ---------------------------------------------------------------------------
// s_c[k] numpy pairwise order (PASSED r2/r4)
// ---------------------------------------------------------------------------
__global__ void sc_kernel(const float* __restrict__ cb, float* __restrict__ sc) {
#pragma clang fp contract(off)
    int k = blockIdx.x * 256 + threadIdx.x;
    const float* p0 = cb + (size_t)k * C_;
    float blk[2];
    for (int h = 0; h < 2; h++) {
        const float* p = p0 + h * 128;
        float r[8];
#pragma unroll
        for (int j = 0; j < 8; j++) { float v = p[j]; r[j] = v * v; }
        for (int i = 8; i < 128; i += 8) {
#pragma unroll
            for (int j = 0; j < 8; j++) { float v = p[i + j]; r[j] += v * v; }
        }
        blk[h] = ((r[0] + r[1]) + (r[2] + r[3])) + ((r[4] + r[5]) + (r[6] + r[7]));
    }
    sc[k] = blk[0] + blk[1];
}

// ---------------------------------------------------------------------------
// Prep: codebook -> fp16 (x1024 exact scale), A-fragment image per K-step.
// ---------------------------------------------------------------------------
__global__ void cbh_prep(const float* __restrict__ cb, unsigned short* __restrict__ cbh) {
    int k = blockIdx.x, c = threadIdx.x;
    float v = cb[(size_t)k * C_ + c] * 1024.0f;
    __half hv = __float2half_rn(v);
    size_t F = ((size_t)(c >> 4) * 1024 + k) * 16 + ((c >> 3) & 1) * 8 + (c & 7);
    cbh[F] = __half_as_ushort(hv);
}

// Prep: cbT[c][k] = cb[k][c] fp32 (refine's coalesced per-lane-k loads)
__global__ void cbT_prep(const float* __restrict__ cb, float* __restrict__ cbT) {
    int c = blockIdx.x, k = threadIdx.x;
    cbT[(size_t)c * K_ + k] = cb[(size_t)k * C_ + c];
}

// ---------------------------------------------------------------------------
// fp16 MFMA score kernel.  Block = 64 pixels, 256 thr (4 waves).
// (structure PASSED r6/r7/r8; setprio T5 added r8)
// NOTE: LDS deliberately 41984 B (3 blocks/CU).  All 40960-B (4 blocks/CU)
// variants failed idx verification 3-for-3 (r3/r4/r5) with identical
// arithmetic - do not retry without a mechanism.
// ---------------------------------------------------------------------------
__global__ __launch_bounds__(256, 4)
void score_kernel(const float* __restrict__ z, const unsigned short* __restrict__ cbh,
                  const float* __restrict__ sc,
                  float* __restrict__ s1o, float* __restrict__ s2o,
                  int* __restrict__ i1o) {
    __shared__ __align__(16) int zw[64 * 132];   // 33792 B
    __shared__ float scs[1024];                  // 4 KB
    __shared__ float ex[4 * 64 * 4];             // 4 KB

    int t = threadIdx.x;
    int w = t >> 6, l = t & 63;
    int n0 = blockIdx.x * 64;

    for (int i = t; i < 1024; i += 256) scs[i] = sc[i] + 0.25f;

    {
        int px = l;
        const float* zp = z + (size_t)(n0 >> 12) * CHW_ + (n0 & 4095) + px;
        int key = (px >> 3) & 3;
#pragma unroll 4
        for (int i = 0; i < 32; i++) {
            int widx = w * 32 + i;
            int c0 = widx * 2;
            float v0 = zp[(size_t)c0 * HW_];
            float v1 = zp[(size_t)(c0 + 1) * HW_];
            unsigned pk = (unsigned)__half_as_ushort(__float2half_rn(v0))
                        | ((unsigned)__half_as_ushort(__float2half_rn(v1)) << 16);
            int c16 = widx >> 2, rem = widx & 3;
            zw[px * 132 + (((c16 ^ key) << 2) | rem)] = pk;
        }
    }
    __syncthreads();

    unsigned b1[2] = { 0xFFFFFFFFu, 0xFFFFFFFFu };
    unsigned b2[2] = { 0xFFFFFFFFu, 0xFFFFFFFFu };

    const unsigned short* ab = cbh + ((size_t)(w * 64 + (l & 31)) * 16 + (l >> 5) * 8);
    short rowmap = (short)((l >> 5) << 2);
    half8 pf[2][2];
#pragma unroll
    for (int i = 0; i < 2; i++) {
        const unsigned short* s = ab + (i & 15) * 16384 + (i >> 4) * 4096;
        pf[i][0] = *(const half8*)(s);
        pf[i][1] = *(const half8*)(s + 512);
    }

    int bkey = ((l & 31) >> 3) & 3;
    int prow0 = (l & 31) * 132;

    for (int chunk = 0; chunk < 4; chunk++) {
        float16 acc[2][2];
#pragma unroll
        for (int mt = 0; mt < 2; mt++)
#pragma unroll
            for (int nt = 0; nt < 2; nt++)
#pragma unroll
                for (int r = 0; r < 16; r++) acc[mt][nt][r] = 0.f;

#pragma unroll
        for (int kk = 0; kk < 16; kk++) {
            int step = chunk * 16 + kk;
            int buf = step & 1;
            half8 a0 = pf[buf][0], a1 = pf[buf][1];
            int ns = step + 2; if (ns > 63) ns = 63;
            {
                const unsigned short* s = ab + (ns & 15) * 16384 + (ns >> 4) * 4096;
                pf[buf][0] = *(const half8*)(s);
                pf[buf][1] = *(const half8*)(s + 512);
            }
            half8 bz[2];
#pragma unroll
            for (int nt = 0; nt < 2; nt++) {
                int c16 = kk * 2 + (l >> 5);
                int word = (nt * 32 * 132 + prow0) + ((c16 ^ bkey) << 2);
                bz[nt] = *(const half8*)((const char*)zw + (size_t)word * 4);
            }
            __builtin_amdgcn_s_setprio(1);
            acc[0][0] = __builtin_amdgcn_mfma_f32_32x32x16_f16(a0, bz[0], acc[0][0], 0, 0, 0);
            acc[0][1] = __builtin_amdgcn_mfma_f32_32x32x16_f16(a0, bz[1], acc[0][1], 0, 0, 0);
            acc[1][0] = __builtin_amdgcn_mfma_f32_32x32x16_f16(a1, bz[0], acc[1][0], 0, 0, 0);
            acc[1][1] = __builtin_amdgcn_mfma_f32_32x32x16_f16(a1, bz[1], acc[1][1], 0, 0, 0);
            __builtin_amdgcn_s_setprio(0);
        }

#pragma unroll
        for (int mt = 0; mt < 2; mt++)
#pragma unroll
            for (int r = 0; r < 16; r++) {
                int scode = chunk * 256 + w * 64 + mt * 32
                          + (r & 3) + ((r >> 2) << 3) + rowmap;
                float sv = scs[scode];
                unsigned emb = (unsigned)((chunk << 5) | (mt << 4) | r);
#pragma unroll
                for (int nt = 0; nt < 2; nt++) {
                    float s = fmaf(-0.001953125f, acc[mt][nt][r], sv);
                    unsigned key = (__float_as_uint(s) & 0xFFFFFF80u) | emb;
                    b2[nt] = umin_(b2[nt], umax_(b1[nt], key));
                    b1[nt] = umin_(b1[nt], key);
                }
            }
    }

#pragma unroll
    for (int nt = 0; nt < 2; nt++) {
        unsigned e1 = b1[nt] & 127u;
        float f1 = __uint_as_float(b1[nt] & 0xFFFFFF80u);
        float f2 = __uint_as_float(b2[nt] & 0xFFFFFF80u);
        int idx = (int)(e1 >> 5) * 256 + w * 64 + (int)((e1 >> 4) & 1) * 32
                + (int)(e1 & 3) + (int)(((e1 >> 2) & 3) << 3) + (int)rowmap;

        float of1 = __shfl_xor(f1, 32, 64);
        int   oi  = __shfl_xor(idx, 32, 64);
        float of2 = __shfl_xor(f2, 32, 64);
        if (of1 < f1 || (of1 == f1 && oi < idx)) {
            f2 = fminf(f1, of2); f1 = of1; idx = oi;
        } else {
            f2 = fminf(f2, of1);
        }

        if (l < 32) {
            int e = (w * 64 + nt * 32 + l) * 4;
            ex[e + 0] = f1;
            ex[e + 1] = f2;
            ((int*)ex)[e + 2] = idx;
        }
    }
    __syncthreads();
    if (t < 64) {
        float cb1 = FLT_BIG, cb2 = FLT_BIG; int cj1 = 0;
#pragma unroll
        for (int wv = 0; wv < 4; wv++) {
            int e = (wv * 64 + t) * 4;
            float nb1 = ex[e + 0];
            float nb2 = ex[e + 1];
            int   nj1 = ((int*)ex)[e + 2];
            if (nb1 < cb1 || (nb1 == cb1 && nj1 < cj1)) {
                cb2 = fminf(cb1, nb2); cb1 = nb1; cj1 = nj1;
            } else {
                cb2 = fminf(cb2, nb1);
            }
        }
        int n = n0 + t;
        s1o[n] = cb1; s2o[n] = cb2; i1o[n] = cj1;
    }
}

// ---------------------------------------------------------------------------
// Flag pass: commit clear winners; compact near-ties.
// ---------------------------------------------------------------------------
__global__ void flag_kernel(const float* __restrict__ s1, const float* __restrict__ s2,
                            const int* __restrict__ i1,
                            int* __restrict__ fidx, float* __restrict__ out_idx,
                            int* __restrict__ list, int* __restrict__ count) {
    int n = blockIdx.x * 256 + threadIdx.x;
    int j = i1[n];
    fidx[n] = j;
    out_idx[n] = (float)j;
    if (s2[n] - s1[n] < GAP_T) {
        int pos = atomicAdd(count, 1);
        list[pos] = n;
    }
}

// ---------------------------------------------------------------------------
// Exact refine, r13: P=2 static epilogues (r12) + __launch_bounds__(256,1).
// r12 post-mortem: VGPR stayed EXACTLY 64 and dur 277us even with fully
// static acc access -> the cap is the MISSING LAUNCH BOUNDS: hipcc budgets
// registers for the default 1024-thread flat-workgroup-size and pins the
// allocator at 64 VGPRs, so 64 VGPRs of f64 acc + temps must spill.
// Evidence: r9 with __launch_bounds__(256,1) got VGPR=112 (allocator DOES
// exceed 64 when bounds are declared); r11/r12 without bounds: 64 both.
// P=2 needs ~100 VGPRs < 112 -> should fit with no spill.
// Mechanism unchanged: ONE cbT sweep amortized over 2 pixels -> L2 traffic
// 2.4GB -> 1.2GB (r8's 72us was L2-BW-bound).  Arithmetic bit-identical
// (passed r11+r12).  FALSIFIABLE SIGNATURE: VGPR ~96-128, not 64.
// HARD FALLBACK (no more theories): if >60us, next round = r8 P=1 verbatim.
// ---------------------------------------------------------------------------
__global__ __launch_bounds__(256, 1)
void refine_kernel(const float* __restrict__ z, const float* __restrict__ cbT,
                   const float* __restrict__ sz, const float* __restrict__ sc,
                   const int* __restrict__ list, const int* __restrict__ count,
                   int* __restrict__ fidx, float* __restrict__ out_idx) {
    __shared__ double zd[4][2][256];           // [wave][px][c] = 16 KB
    int w = threadIdx.x >> 6, l = threadIdx.x & 63;
    int cnt = *count;
    if (cnt > 65536) cnt = 65536;
    int wid = blockIdx.x * 4 + w;              // 0..8191
    for (int base = wid * 2; base < cnt; base += 8192 * 2) {
        int np = cnt - base; if (np > 2) np = 2;
        int n0 = list[base];
        int n1 = list[base + (np > 1 ? 1 : 0)];
        {
            const float* zp0 = z + (size_t)(n0 >> 12) * CHW_ + (n0 & 4095);
            const float* zp1 = z + (size_t)(n1 >> 12) * CHW_ + (n1 & 4095);
#pragma unroll
            for (int j = 0; j < 4; j++) {
                zd[w][0][l * 4 + j] = (double)zp0[(size_t)(l * 4 + j) * HW_];
                zd[w][1][l * 4 + j] = (double)zp1[(size_t)(l * 4 + j) * HW_];
            }
        }
        asm volatile("s_waitcnt lgkmcnt(0)" ::: "memory");

        double acc0[16], acc1[16];
#pragma unroll
        for (int a = 0; a < 16; a++) { acc0[a] = 0.0; acc1[a] = 0.0; }

        for (int c = 0; c < 256; c++) {
            double zc0 = zd[w][0][c];
            double zc1 = zd[w][1][c];
            const float* cp = cbT + (size_t)c * K_ + l * 4;
#pragma unroll
            for (int it = 0; it < 4; it++) {
                float4 cv = *(const float4*)(cp + it * 256);
                double cx = (double)cv.x, cy = (double)cv.y;
                double cz = (double)cv.z, cw = (double)cv.w;
                acc0[it * 4 + 0] += zc0 * cx;
                acc0[it * 4 + 1] += zc0 * cy;
                acc0[it * 4 + 2] += zc0 * cz;
                acc0[it * 4 + 3] += zc0 * cw;
                acc1[it * 4 + 0] += zc1 * cx;
                acc1[it * 4 + 1] += zc1 * cy;
                acc1[it * 4 + 2] += zc1 * cz;
                acc1[it * 4 + 3] += zc1 * cw;
            }
        }

        // epilogue p=0: hard-wired acc0/n0 (always valid: np >= 1)
        {
            float szv = sz[n0];
            float best = FLT_BIG; int bidx = K_;
#pragma unroll
            for (int it = 0; it < 4; it++)
#pragma unroll
                for (int s = 0; s < 4; s++) {
                    int k = it * 256 + l * 4 + s;
                    float dotf = (float)acc0[it * 4 + s];
                    float dq = (szv + sc[k]) - 2.0f * dotf;
                    if (dq < best || (dq == best && k < bidx)) { best = dq; bidx = k; }
                }
#pragma unroll
            for (int off = 32; off > 0; off >>= 1) {
                float ob = __shfl_xor(best, off, 64);
                int   oj = __shfl_xor(bidx, off, 64);
                if (ob < best || (ob == best && oj < bidx)) { best = ob; bidx = oj; }
            }
            if (l == 0) { fidx[n0] = bidx; out_idx[n0] = (float)bidx; }
        }
        // epilogue p=1: hard-wired acc1/n1 (guarded)
        if (np > 1) {
            float szv = sz[n1];
            float best = FLT_BIG; int bidx = K_;
#pragma unroll
            for (int it = 0; it < 4; it++)
#pragma unroll
                for (int s = 0; s < 4; s++) {
                    int k = it * 256 + l * 4 + s;
                    float dotf = (float)acc1[it * 4 + s];
                    float dq = (szv + sc[k]) - 2.0f * dotf;
                    if (dq < best || (dq == best && k < bidx)) { best = dq; bidx = k; }
                }
#pragma unroll
            for (int off = 32; off > 0; off >>= 1) {
                float ob = __shfl_xor(best, off, 64);
                int   oj = __shfl_xor(bidx, off, 64);
                if (ob < best || (ob == best && oj < bidx)) { best = ob; bidx = oj; }
            }
            if (l == 0) { fidx[n1] = bidx; out_idx[n1] = (float)bidx; }
        }
        asm volatile("s_waitcnt lgkmcnt(0)" ::: "memory");
    }
}

// ---------------------------------------------------------------------------
// Gather zq -> NCHW output + loss partials (float4 version, PASSED r8)
// ---------------------------------------------------------------------------
__global__ void output_kernel(const float* __restrict__ z, const float* __restrict__ cb,
                              const int* __restrict__ fidx,
                              float* __restrict__ out0, double* __restrict__ partials) {
    __shared__ int sidx[64];
    __shared__ double red[256];
    int t = threadIdx.x;
    int blk = blockIdx.x;
    int n0 = blk * 64;
    if (t < 64) sidx[t] = fidx[n0 + t];
    __syncthreads();
    int batch = n0 >> 12, s0 = n0 & 4095;
    const float* zbase = z + (size_t)batch * CHW_ + s0;
    float* obase = out0 + (size_t)batch * CHW_ + s0;
    int ig = (t & 15) * 4;
    int cg = (t >> 4) * 4;
    const float* r0 = cb + (size_t)sidx[ig + 0] * C_;
    const float* r1 = cb + (size_t)sidx[ig + 1] * C_;
    const float* r2 = cb + (size_t)sidx[ig + 2] * C_;
    const float* r3 = cb + (size_t)sidx[ig + 3] * C_;
    double sum = 0.0;
#pragma unroll
    for (int pass = 0; pass < 4; pass++) {
        int c0 = pass * 64 + cg;
        float4 q0 = *(const float4*)(r0 + c0);
        float4 q1 = *(const float4*)(r1 + c0);
        float4 q2 = *(const float4*)(r2 + c0);
        float4 q3 = *(const float4*)(r3 + c0);
        float a0[4] = { q0.x, q0.y, q0.z, q0.w };
        float a1[4] = { q1.x, q1.y, q1.z, q1.w };
        float a2[4] = { q2.x, q2.y, q2.z, q2.w };
        float a3[4] = { q3.x, q3.y, q3.z, q3.w };
#pragma unroll
        for (int j = 0; j < 4; j++) {
            size_t off = (size_t)(c0 + j) * HW_ + ig;
            float4 zv = *(const float4*)(zbase + off);
            float4 qq;
            qq.x = a0[j]; qq.y = a1[j]; qq.z = a2[j]; qq.w = a3[j];
            *(float4*)(obase + off) = qq;
            float d0 = qq.x - zv.x, d1 = qq.y - zv.y;
            float d2 = qq.z - zv.z, d3 = qq.w - zv.w;
            sum += (double)d0 * (double)d0;
            sum += (double)d1 * (double)d1;
            sum += (double)d2 * (double)d2;
            sum += (double)d3 * (double)d3;
        }
    }
    red[t] = sum;
    __syncthreads();
    for (int s = 128; s > 0; s >>= 1) {
        if (t < s) red[t] += red[t + s];
        __syncthreads();
    }
    if (t == 0) partials[blk] = red[0];
}

__global__ void loss_kernel(const double* __restrict__ partials, float* __restrict__ out_loss) {
    __shared__ double red[256];
    int t = threadIdx.x;
    double s = 0.0;
    for (int r = t; r < 1024; r += 256) s += partials[r];
    red[t] = s;
    __syncthreads();
    for (int k = 128; k > 0; k >>= 1) {
        if (t < k) red[t] += red[t + k];
        __syncthreads();
    }
    if (t == 0) *out_loss = (float)(0.75 * red[0] / 16777216.0);
}

// ---------------------------------------------------------------------------
extern "C" void kernel_launch(void* const* d_in, const int* in_sizes, int n_in,
                              void* d_out, int out_size, void* d_ws, size_t ws_size,
                              hipStream_t stream) {
    const float* z  = (const float*)d_in[0];
    const float* cb = (const float*)d_in[1];

    float* out0     = (float*)d_out;
    float* out_idx  = out0 + (size_t)16777216;
    float* out_loss = out0 + (size_t)16842752;

    char* w = (char*)d_ws;
    double* partials = (double*)w;                       //       0 .. 8192
    float*  sc   = (float*)(w + 8192);                   //    8192 .. 12288
    float*  sz   = (float*)(w + 12288);                  //   12288 .. 274432
    float*  s1   = (float*)(w + 274432);
    float*  s2   = (float*)(w + 536576);
    int*    i1   = (int*)  (w + 798720);
    int*    fidx = (int*)  (w + 1060864);
    int*    count= (int*)  (w + 1323008);
    int*    list = (int*)  (w + 1323264);                // 256 KB
    unsigned short* cbh = (unsigned short*)(w + 1585408);// 512 KB
    float*  cbT  = (float*)(w + 2109952);                // 1 MB -> ends 3158528
    float*  rp   = (float*)(w + 3158528);                // 4 MB sz partials -> ends 7352832

    hipMemsetAsync(count, 0, 4, stream);
    szp_kernel   <<<4096, 256, 0, stream>>>(z, rp);
    szc_kernel   <<<256,  256, 0, stream>>>(rp, sz);
    sc_kernel    <<<4,    256, 0, stream>>>(cb, sc);
    cbh_prep     <<<1024, 256, 0, stream>>>(cb, cbh);
    cbT_prep     <<<256, 1024, 0, stream>>>(cb, cbT);
    score_kernel <<<1024, 256, 0, stream>>>(z, cbh, sc, s1, s2, i1);
    flag_kernel  <<<256,  256, 0, stream>>>(s1, s2, i1, fidx, out_idx, list, count);
    refine_kernel<<<2048, 256, 0, stream>>>(z, cbT, sz, sc, list, count, fidx, out_idx);
    output_kernel<<<1024, 256, 0, stream>>>(z, cb, fidx, out0, partials);
    loss_kernel  <<<1,    256, 0, stream>>>(partials, out_loss);
}

// Round 14
// 321.553 us; speedup vs baseline: 1.5277x; 1.5277x over previous
//
#include <hip/hip_runtime.h>
#include <hip/hip_fp16.h>

#define B_    16
#define C_    256
#define HW_   4096
#define CHW_  1048576
#define N_    65536
#define K_    1024
#define FLT_BIG 3.402823466e38f
#define GAP_T  1.2e-4f   // ref fp32-quant floor 6.1e-5 + 6sigma fp16 score err ~3.1e-5 + key-pack 8e-6 + margin

typedef _Float16 half8 __attribute__((ext_vector_type(8)));
typedef float   float16 __attribute__((ext_vector_type(16)));

__device__ __forceinline__ unsigned umin_(unsigned a, unsigned b) { return a < b ? a : b; }
__device__ __forceinline__ unsigned umax_(unsigned a, unsigned b) { return a > b ? a : b; }

// ---------------------------------------------------------------------------
// s_z split into 16x-parallel partial pass + exact combine (PASSED r7).
// ---------------------------------------------------------------------------
__global__ void szp_kernel(const float* __restrict__ z, float* __restrict__ rp) {
#pragma clang fp contract(off)
    int hj = blockIdx.x >> 8;              // 0..15  (h = hj>>3, j = hj&7)
    int bx = blockIdx.x & 255;
    int n  = bx * 256 + threadIdx.x;
    int h = hj >> 3, j = hj & 7;
    const float* p = z + (size_t)(n >> 12) * CHW_ + (n & 4095)
                       + (size_t)(h * 128 + j) * HW_;
    float v = p[0];
    float r = v * v;
    for (int s = 1; s < 16; s++) {
        float u = p[(size_t)(s * 8) * HW_];
        r += u * u;
    }
    rp[(size_t)hj * N_ + n] = r;
}

__global__ void szc_kernel(const float* __restrict__ rp, float* __restrict__ sz) {
#pragma clang fp contract(off)
    int n = blockIdx.x * 256 + threadIdx.x;
    float blk[2];
    for (int h = 0; h < 2; h++) {
        const float* b = rp + (size_t)(h * 8) * N_ + n;
        float r0 = b[0 * N_], r1 = b[1 * N_], r2 = b[2 * N_], r3 = b[3 * N_];
        float r4 = b[4 * N_], r5 = b[5 * N_], r6 = b[6 * N_], r7 = b[7 * N_];
        blk[h] = ((r0 + r1) + (r2 + r3)) + ((r4 + r5) + (r6 + r7));
    }
    sz[n] = blk[0] + blk[1];
}

// ---------------------------------------------------------------------------
// s_c[k] numpy pairwise order (PASSED r2/r4)
// ---------------------------------------------------------------------------
__global__ void sc_kernel(const float* __restrict__ cb, float* __restrict__ sc) {
#pragma clang fp contract(off)
    int k = blockIdx.x * 256 + threadIdx.x;
    const float* p0 = cb + (size_t)k * C_;
    float blk[2];
    for (int h = 0; h < 2; h++) {
        const float* p = p0 + h * 128;
        float r[8];
#pragma unroll
        for (int j = 0; j < 8; j++) { float v = p[j]; r[j] = v * v; }
        for (int i = 8; i < 128; i += 8) {
#pragma unroll
            for (int j = 0; j < 8; j++) { float v = p[i + j]; r[j] += v * v; }
        }
        blk[h] = ((r[0] + r[1]) + (r[2] + r[3])) + ((r[4] + r[5]) + (r[6] + r[7]));
    }
    sc[k] = blk[0] + blk[1];
}

// ---------------------------------------------------------------------------
// Prep: codebook -> fp16 (x1024 exact scale), A-fragment image per K-step.
// ---------------------------------------------------------------------------
__global__ void cbh_prep(const float* __restrict__ cb, unsigned short* __restrict__ cbh) {
    int k = blockIdx.x, c = threadIdx.x;
    float v = cb[(size_t)k * C_ + c] * 1024.0f;
    __half hv = __float2half_rn(v);
    size_t F = ((size_t)(c >> 4) * 1024 + k) * 16 + ((c >> 3) & 1) * 8 + (c & 7);
    cbh[F] = __half_as_ushort(hv);
}

// Prep: cbT[c][k] = cb[k][c] fp32 (refine's coalesced per-lane-k loads)
__global__ void cbT_prep(const float* __restrict__ cb, float* __restrict__ cbT) {
    int c = blockIdx.x, k = threadIdx.x;
    cbT[(size_t)c * K_ + k] = cb[(size_t)k * C_ + c];
}

// ---------------------------------------------------------------------------
// fp16 MFMA score kernel.  Block = 64 pixels, 256 thr (4 waves).
// (structure PASSED r6/r7/r8; setprio T5 added r8)
// NOTE: LDS deliberately 41984 B (3 blocks/CU).  All 40960-B (4 blocks/CU)
// variants failed idx verification 3-for-3 (r3/r4/r5) with identical
// arithmetic - do not retry without a mechanism.
// ---------------------------------------------------------------------------
__global__ __launch_bounds__(256, 4)
void score_kernel(const float* __restrict__ z, const unsigned short* __restrict__ cbh,
                  const float* __restrict__ sc,
                  float* __restrict__ s1o, float* __restrict__ s2o,
                  int* __restrict__ i1o) {
    __shared__ __align__(16) int zw[64 * 132];   // 33792 B
    __shared__ float scs[1024];                  // 4 KB
    __shared__ float ex[4 * 64 * 4];             // 4 KB

    int t = threadIdx.x;
    int w = t >> 6, l = t & 63;
    int n0 = blockIdx.x * 64;

    for (int i = t; i < 1024; i += 256) scs[i] = sc[i] + 0.25f;

    {
        int px = l;
        const float* zp = z + (size_t)(n0 >> 12) * CHW_ + (n0 & 4095) + px;
        int key = (px >> 3) & 3;
#pragma unroll 4
        for (int i = 0; i < 32; i++) {
            int widx = w * 32 + i;
            int c0 = widx * 2;
            float v0 = zp[(size_t)c0 * HW_];
            float v1 = zp[(size_t)(c0 + 1) * HW_];
            unsigned pk = (unsigned)__half_as_ushort(__float2half_rn(v0))
                        | ((unsigned)__half_as_ushort(__float2half_rn(v1)) << 16);
            int c16 = widx >> 2, rem = widx & 3;
            zw[px * 132 + (((c16 ^ key) << 2) | rem)] = pk;
        }
    }
    __syncthreads();

    unsigned b1[2] = { 0xFFFFFFFFu, 0xFFFFFFFFu };
    unsigned b2[2] = { 0xFFFFFFFFu, 0xFFFFFFFFu };

    const unsigned short* ab = cbh + ((size_t)(w * 64 + (l & 31)) * 16 + (l >> 5) * 8);
    short rowmap = (short)((l >> 5) << 2);
    half8 pf[2][2];
#pragma unroll
    for (int i = 0; i < 2; i++) {
        const unsigned short* s = ab + (i & 15) * 16384 + (i >> 4) * 4096;
        pf[i][0] = *(const half8*)(s);
        pf[i][1] = *(const half8*)(s + 512);
    }

    int bkey = ((l & 31) >> 3) & 3;
    int prow0 = (l & 31) * 132;

    for (int chunk = 0; chunk < 4; chunk++) {
        float16 acc[2][2];
#pragma unroll
        for (int mt = 0; mt < 2; mt++)
#pragma unroll
            for (int nt = 0; nt < 2; nt++)
#pragma unroll
                for (int r = 0; r < 16; r++) acc[mt][nt][r] = 0.f;

#pragma unroll
        for (int kk = 0; kk < 16; kk++) {
            int step = chunk * 16 + kk;
            int buf = step & 1;
            half8 a0 = pf[buf][0], a1 = pf[buf][1];
            int ns = step + 2; if (ns > 63) ns = 63;
            {
                const unsigned short* s = ab + (ns & 15) * 16384 + (ns >> 4) * 4096;
                pf[buf][0] = *(const half8*)(s);
                pf[buf][1] = *(const half8*)(s + 512);
            }
            half8 bz[2];
#pragma unroll
            for (int nt = 0; nt < 2; nt++) {
                int c16 = kk * 2 + (l >> 5);
                int word = (nt * 32 * 132 + prow0) + ((c16 ^ bkey) << 2);
                bz[nt] = *(const half8*)((const char*)zw + (size_t)word * 4);
            }
            __builtin_amdgcn_s_setprio(1);
            acc[0][0] = __builtin_amdgcn_mfma_f32_32x32x16_f16(a0, bz[0], acc[0][0], 0, 0, 0);
            acc[0][1] = __builtin_amdgcn_mfma_f32_32x32x16_f16(a0, bz[1], acc[0][1], 0, 0, 0);
            acc[1][0] = __builtin_amdgcn_mfma_f32_32x32x16_f16(a1, bz[0], acc[1][0], 0, 0, 0);
            acc[1][1] = __builtin_amdgcn_mfma_f32_32x32x16_f16(a1, bz[1], acc[1][1], 0, 0, 0);
            __builtin_amdgcn_s_setprio(0);
        }

#pragma unroll
        for (int mt = 0; mt < 2; mt++)
#pragma unroll
            for (int r = 0; r < 16; r++) {
                int scode = chunk * 256 + w * 64 + mt * 32
                          + (r & 3) + ((r >> 2) << 3) + rowmap;
                float sv = scs[scode];
                unsigned emb = (unsigned)((chunk << 5) | (mt << 4) | r);
#pragma unroll
                for (int nt = 0; nt < 2; nt++) {
                    float s = fmaf(-0.001953125f, acc[mt][nt][r], sv);
                    unsigned key = (__float_as_uint(s) & 0xFFFFFF80u) | emb;
                    b2[nt] = umin_(b2[nt], umax_(b1[nt], key));
                    b1[nt] = umin_(b1[nt], key);
                }
            }
    }

#pragma unroll
    for (int nt = 0; nt < 2; nt++) {
        unsigned e1 = b1[nt] & 127u;
        float f1 = __uint_as_float(b1[nt] & 0xFFFFFF80u);
        float f2 = __uint_as_float(b2[nt] & 0xFFFFFF80u);
        int idx = (int)(e1 >> 5) * 256 + w * 64 + (int)((e1 >> 4) & 1) * 32
                + (int)(e1 & 3) + (int)(((e1 >> 2) & 3) << 3) + (int)rowmap;

        float of1 = __shfl_xor(f1, 32, 64);
        int   oi  = __shfl_xor(idx, 32, 64);
        float of2 = __shfl_xor(f2, 32, 64);
        if (of1 < f1 || (of1 == f1 && oi < idx)) {
            f2 = fminf(f1, of2); f1 = of1; idx = oi;
        } else {
            f2 = fminf(f2, of1);
        }

        if (l < 32) {
            int e = (w * 64 + nt * 32 + l) * 4;
            ex[e + 0] = f1;
            ex[e + 1] = f2;
            ((int*)ex)[e + 2] = idx;
        }
    }
    __syncthreads();
    if (t < 64) {
        float cb1 = FLT_BIG, cb2 = FLT_BIG; int cj1 = 0;
#pragma unroll
        for (int wv = 0; wv < 4; wv++) {
            int e = (wv * 64 + t) * 4;
            float nb1 = ex[e + 0];
            float nb2 = ex[e + 1];
            int   nj1 = ((int*)ex)[e + 2];
            if (nb1 < cb1 || (nb1 == cb1 && nj1 < cj1)) {
                cb2 = fminf(cb1, nb2); cb1 = nb1; cj1 = nj1;
            } else {
                cb2 = fminf(cb2, nb1);
            }
        }
        int n = n0 + t;
        s1o[n] = cb1; s2o[n] = cb2; i1o[n] = cj1;
    }
}

// ---------------------------------------------------------------------------
// Flag pass: commit clear winners; compact near-ties.
// ---------------------------------------------------------------------------
__global__ void flag_kernel(const float* __restrict__ s1, const float* __restrict__ s2,
                            const int* __restrict__ i1,
                            int* __restrict__ fidx, float* __restrict__ out_idx,
                            int* __restrict__ list, int* __restrict__ count) {
    int n = blockIdx.x * 256 + threadIdx.x;
    int j = i1[n];
    fidx[n] = j;
    out_idx[n] = (float)j;
    if (s2[n] - s1[n] < GAP_T) {
        int pos = atomicAdd(count, 1);
        list[pos] = n;
    }
}

// ---------------------------------------------------------------------------
// Exact refine, r14: BLOCK-level cbT sharing via LDS (register-safe).
// P>1-in-registers is CLOSED: r9 (P=4, spill), r11/r12/r13 (P=2, acc pinned
// to L2-scratch at VGPR=64 regardless of static access or launch bounds;
// FETCH unchanged + VALUBusy 5.5% + ~290us L2-roundtrip model = scratch in
// L2).  New mechanism: each wave keeps r8's PROVEN footprint (one pixel,
// acc[16] = 32 VGPRs); the block's 4 waves share ONE cbT sweep staged
// through LDS in 8-row (32KB) tiles.  L2 traffic: 600 blocks x 1MB = 600MB
// vs r8's 2.4GB (4x).  Barriers are block-uniform (cnt same for all
// threads; loop bound depends only on blockIdx).  Tail waves stage+barrier
// but don't write.  Arithmetic bit-identical to r4-verified chain: c
// ascends 0..255 (tiles x rows in order), identical float4 values (exact
// copies through LDS), identical k<->lane map, identical epilogue.
// cbt_s rows padded (+4 floats) -> LDS 41088, clear of the 40960 boundary.
// FALLBACK: if >60us or FAIL, next round = r8 refine verbatim, closed.
// ---------------------------------------------------------------------------
__global__ void refine_kernel(const float* __restrict__ z, const float* __restrict__ cbT,
                              const float* __restrict__ sz, const float* __restrict__ sc,
                              const int* __restrict__ list, const int* __restrict__ count,
                              int* __restrict__ fidx, float* __restrict__ out_idx) {
    __shared__ __align__(16) float cbt_s[8][1028];  // 8 c-rows x (1024+4 pad), 32896 B
    __shared__ double zd[4][256];                   // per-wave pixel channels, 8 KB
    int t = threadIdx.x;
    int w = t >> 6, l = t & 63;
    int cnt = *count;
    if (cnt > 65536) cnt = 65536;
    for (int gbase = blockIdx.x * 4; gbase < cnt; gbase += 2048 * 4) {
        int myi = gbase + w;
        bool valid = myi < cnt;
        int n = list[valid ? myi : gbase];
        {
            const float* zp = z + (size_t)(n >> 12) * CHW_ + (n & 4095);
#pragma unroll
            for (int j = 0; j < 4; j++)
                zd[w][l * 4 + j] = (double)zp[(size_t)(l * 4 + j) * HW_];
        }
        asm volatile("s_waitcnt lgkmcnt(0)" ::: "memory");

        double acc[16];
#pragma unroll
        for (int a = 0; a < 16; a++) acc[a] = 0.0;

        for (int cc = 0; cc < 256; cc += 8) {
            // stage 8 cbT rows (8 x 1024 floats): 2048 float4s over 256 thr
            __syncthreads();   // all waves done reading previous tile
#pragma unroll
            for (int i = 0; i < 8; i++) {
                int f  = i * 256 + t;           // float4 index 0..2047
                int r  = f >> 8;                // row 0..7
                int c4 = f & 255;               // float4-col 0..255
                *(float4*)&cbt_s[r][c4 * 4] =
                    *(const float4*)(cbT + (size_t)(cc + r) * K_ + c4 * 4);
            }
            __syncthreads();
#pragma unroll
            for (int r = 0; r < 8; r++) {
                double zc = zd[w][cc + r];
                const float* cp = &cbt_s[r][l * 4];
#pragma unroll
                for (int it = 0; it < 4; it++) {
                    float4 cv = *(const float4*)(cp + it * 256);
                    acc[it * 4 + 0] += zc * (double)cv.x;
                    acc[it * 4 + 1] += zc * (double)cv.y;
                    acc[it * 4 + 2] += zc * (double)cv.z;
                    acc[it * 4 + 3] += zc * (double)cv.w;
                }
            }
        }

        float szv = sz[n];
        float best = FLT_BIG; int bidx = K_;
#pragma unroll
        for (int it = 0; it < 4; it++)
#pragma unroll
            for (int s = 0; s < 4; s++) {
                int k = it * 256 + l * 4 + s;
                float dotf = (float)acc[it * 4 + s];
                float dq = (szv + sc[k]) - 2.0f * dotf;
                if (dq < best || (dq == best && k < bidx)) { best = dq; bidx = k; }
            }
#pragma unroll
        for (int off = 32; off > 0; off >>= 1) {
            float ob = __shfl_xor(best, off, 64);
            int   oj = __shfl_xor(bidx, off, 64);
            if (ob < best || (ob == best && oj < bidx)) { best = ob; bidx = oj; }
        }
        if (valid && l == 0) { fidx[n] = bidx; out_idx[n] = (float)bidx; }
        __syncthreads();   // all waves done with zd/epilogue before next group
    }
}

// ---------------------------------------------------------------------------
// Gather zq -> NCHW output + loss partials (float4 version, PASSED r8)
// ---------------------------------------------------------------------------
__global__ void output_kernel(const float* __restrict__ z, const float* __restrict__ cb,
                              const int* __restrict__ fidx,
                              float* __restrict__ out0, double* __restrict__ partials) {
    __shared__ int sidx[64];
    __shared__ double red[256];
    int t = threadIdx.x;
    int blk = blockIdx.x;
    int n0 = blk * 64;
    if (t < 64) sidx[t] = fidx[n0 + t];
    __syncthreads();
    int batch = n0 >> 12, s0 = n0 & 4095;
    const float* zbase = z + (size_t)batch * CHW_ + s0;
    float* obase = out0 + (size_t)batch * CHW_ + s0;
    int ig = (t & 15) * 4;
    int cg = (t >> 4) * 4;
    const float* r0 = cb + (size_t)sidx[ig + 0] * C_;
    const float* r1 = cb + (size_t)sidx[ig + 1] * C_;
    const float* r2 = cb + (size_t)sidx[ig + 2] * C_;
    const float* r3 = cb + (size_t)sidx[ig + 3] * C_;
    double sum = 0.0;
#pragma unroll
    for (int pass = 0; pass < 4; pass++) {
        int c0 = pass * 64 + cg;
        float4 q0 = *(const float4*)(r0 + c0);
        float4 q1 = *(const float4*)(r1 + c0);
        float4 q2 = *(const float4*)(r2 + c0);
        float4 q3 = *(const float4*)(r3 + c0);
        float a0[4] = { q0.x, q0.y, q0.z, q0.w };
        float a1[4] = { q1.x, q1.y, q1.z, q1.w };
        float a2[4] = { q2.x, q2.y, q2.z, q2.w };
        float a3[4] = { q3.x, q3.y, q3.z, q3.w };
#pragma unroll
        for (int j = 0; j < 4; j++) {
            size_t off = (size_t)(c0 + j) * HW_ + ig;
            float4 zv = *(const float4*)(zbase + off);
            float4 qq;
            qq.x = a0[j]; qq.y = a1[j]; qq.z = a2[j]; qq.w = a3[j];
            *(float4*)(obase + off) = qq;
            float d0 = qq.x - zv.x, d1 = qq.y - zv.y;
            float d2 = qq.z - zv.z, d3 = qq.w - zv.w;
            sum += (double)d0 * (double)d0;
            sum += (double)d1 * (double)d1;
            sum += (double)d2 * (double)d2;
            sum += (double)d3 * (double)d3;
        }
    }
    red[t] = sum;
    __syncthreads();
    for (int s = 128; s > 0; s >>= 1) {
        if (t < s) red[t] += red[t + s];
        __syncthreads();
    }
    if (t == 0) partials[blk] = red[0];
}

__global__ void loss_kernel(const double* __restrict__ partials, float* __restrict__ out_loss) {
    __shared__ double red[256];
    int t = threadIdx.x;
    double s = 0.0;
    for (int r = t; r < 1024; r += 256) s += partials[r];
    red[t] = s;
    __syncthreads();
    for (int k = 128; k > 0; k >>= 1) {
        if (t < k) red[t] += red[t + k];
        __syncthreads();
    }
    if (t == 0) *out_loss = (float)(0.75 * red[0] / 16777216.0);
}

// ---------------------------------------------------------------------------
extern "C" void kernel_launch(void* const* d_in, const int* in_sizes, int n_in,
                              void* d_out, int out_size, void* d_ws, size_t ws_size,
                              hipStream_t stream) {
    const float* z  = (const float*)d_in[0];
    const float* cb = (const float*)d_in[1];

    float* out0     = (float*)d_out;
    float* out_idx  = out0 + (size_t)16777216;
    float* out_loss = out0 + (size_t)16842752;

    char* w = (char*)d_ws;
    double* partials = (double*)w;                       //       0 .. 8192
    float*  sc   = (float*)(w + 8192);                   //    8192 .. 12288
    float*  sz   = (float*)(w + 12288);                  //   12288 .. 274432
    float*  s1   = (float*)(w + 274432);
    float*  s2   = (float*)(w + 536576);
    int*    i1   = (int*)  (w + 798720);
    int*    fidx = (int*)  (w + 1060864);
    int*    count= (int*)  (w + 1323008);
    int*    list = (int*)  (w + 1323264);                // 256 KB
    unsigned short* cbh = (unsigned short*)(w + 1585408);// 512 KB
    float*  cbT  = (float*)(w + 2109952);                // 1 MB -> ends 3158528
    float*  rp   = (float*)(w + 3158528);                // 4 MB sz partials -> ends 7352832

    hipMemsetAsync(count, 0, 4, stream);
    szp_kernel   <<<4096, 256, 0, stream>>>(z, rp);
    szc_kernel   <<<256,  256, 0, stream>>>(rp, sz);
    sc_kernel    <<<4,    256, 0, stream>>>(cb, sc);
    cbh_prep     <<<1024, 256, 0, stream>>>(cb, cbh);
    cbT_prep     <<<256, 1024, 0, stream>>>(cb, cbT);
    score_kernel <<<1024, 256, 0, stream>>>(z, cbh, sc, s1, s2, i1);
    flag_kernel  <<<256,  256, 0, stream>>>(s1, s2, i1, fidx, out_idx, list, count);
    refine_kernel<<<2048, 256, 0, stream>>>(z, cbT, sz, sc, list, count, fidx, out_idx);
    output_kernel<<<1024, 256, 0, stream>>>(z, cb, fidx, out0, partials);
    loss_kernel  <<<1,    256, 0, stream>>>(partials, out_loss);
}

// Round 15
// 279.299 us; speedup vs baseline: 1.7588x; 1.1513x over previous
//
#include <hip/hip_runtime.h>
#include <hip/hip_fp16.h>

#define B_    16
#define C_    256
#define HW_   4096
#define CHW_  1048576
#define N_    65536
#define K_    1024
#define FLT_BIG 3.402823466e38f
#define GAP_T  1.2e-4f   // ref fp32-quant floor 6.1e-5 + 6sigma fp16 score err ~3.1e-5 + key-pack 8e-6 + margin

typedef _Float16 half8 __attribute__((ext_vector_type(8)));
typedef float   float16 __attribute__((ext_vector_type(16)));

__device__ __forceinline__ unsigned umin_(unsigned a, unsigned b) { return a < b ? a : b; }
__device__ __forceinline__ unsigned umax_(unsigned a, unsigned b) { return a > b ? a : b; }

// ---------------------------------------------------------------------------
// s_z partial pass (PASSED r7): thread owns ONE (h,j) chain of pixel n,
// sequential i-order.  Combine (numpy-pairwise exact) now fused into flag.
// ---------------------------------------------------------------------------
__global__ void szp_kernel(const float* __restrict__ z, float* __restrict__ rp) {
#pragma clang fp contract(off)
    int hj = blockIdx.x >> 8;              // 0..15  (h = hj>>3, j = hj&7)
    int bx = blockIdx.x & 255;
    int n  = bx * 256 + threadIdx.x;
    int h = hj >> 3, j = hj & 7;
    const float* p = z + (size_t)(n >> 12) * CHW_ + (n & 4095)
                       + (size_t)(h * 128 + j) * HW_;
    float v = p[0];
    float r = v * v;
    for (int s = 1; s < 16; s++) {
        float u = p[(size_t)(s * 8) * HW_];
        r += u * u;
    }
    rp[(size_t)hj * N_ + n] = r;
}

// ---------------------------------------------------------------------------
// s_c[k] numpy pairwise order (PASSED r2/r4)
// ---------------------------------------------------------------------------
__global__ void sc_kernel(const float* __restrict__ cb, float* __restrict__ sc) {
#pragma clang fp contract(off)
    int k = blockIdx.x * 256 + threadIdx.x;
    const float* p0 = cb + (size_t)k * C_;
    float blk[2];
    for (int h = 0; h < 2; h++) {
        const float* p = p0 + h * 128;
        float r[8];
#pragma unroll
        for (int j = 0; j < 8; j++) { float v = p[j]; r[j] = v * v; }
        for (int i = 8; i < 128; i += 8) {
#pragma unroll
            for (int j = 0; j < 8; j++) { float v = p[i + j]; r[j] += v * v; }
        }
        blk[h] = ((r[0] + r[1]) + (r[2] + r[3])) + ((r[4] + r[5]) + (r[6] + r[7]));
    }
    sc[k] = blk[0] + blk[1];
}

// ---------------------------------------------------------------------------
// Prep: codebook -> fp16 (x1024 exact scale), A-fragment image per K-step.
// ---------------------------------------------------------------------------
__global__ void cbh_prep(const float* __restrict__ cb, unsigned short* __restrict__ cbh) {
    int k = blockIdx.x, c = threadIdx.x;
    float v = cb[(size_t)k * C_ + c] * 1024.0f;
    __half hv = __float2half_rn(v);
    size_t F = ((size_t)(c >> 4) * 1024 + k) * 16 + ((c >> 3) & 1) * 8 + (c & 7);
    cbh[F] = __half_as_ushort(hv);
}

// ---------------------------------------------------------------------------
// Prep: cbT[c][k] = cb[k][c] fp32.  r15: LDS-tiled 64x64 transpose -
// coalesced reads AND writes (old version read at stride-1KB/lane).
// Values are exact copies (bit-identical).  Grid 64 blocks x 256 thr.
// ---------------------------------------------------------------------------
__global__ void cbT_prep(const float* __restrict__ cb, float* __restrict__ cbT) {
    __shared__ float tile[64][65];
    int bx = blockIdx.x & 15;              // k-tile 0..15
    int by = blockIdx.x >> 4;              // c-tile 0..3
    int tc = threadIdx.x & 63, tr = threadIdx.x >> 6;
#pragma unroll
    for (int i = 0; i < 16; i++) {
        int k = tr + i * 4;                // 0..63
        tile[k][tc] = cb[(size_t)(bx * 64 + k) * C_ + by * 64 + tc];
    }
    __syncthreads();
#pragma unroll
    for (int i = 0; i < 16; i++) {
        int cc = tr + i * 4;               // 0..63
        cbT[(size_t)(by * 64 + cc) * K_ + bx * 64 + tc] = tile[tc][cc];
    }
}

// ---------------------------------------------------------------------------
// fp16 MFMA score kernel.  Block = 64 pixels, 256 thr (4 waves).
// (structure PASSED r6/r7/r8; setprio T5 added r8)
// NOTE: LDS deliberately 41984 B (3 blocks/CU).  All 40960-B (4 blocks/CU)
// variants failed idx verification 3-for-3 (r3/r4/r5) with identical
// arithmetic - do not retry without a mechanism.
// ---------------------------------------------------------------------------
__global__ __launch_bounds__(256, 4)
void score_kernel(const float* __restrict__ z, const unsigned short* __restrict__ cbh,
                  const float* __restrict__ sc,
                  float* __restrict__ s1o, float* __restrict__ s2o,
                  int* __restrict__ i1o) {
    __shared__ __align__(16) int zw[64 * 132];   // 33792 B
    __shared__ float scs[1024];                  // 4 KB
    __shared__ float ex[4 * 64 * 4];             // 4 KB

    int t = threadIdx.x;
    int w = t >> 6, l = t & 63;
    int n0 = blockIdx.x * 64;

    for (int i = t; i < 1024; i += 256) scs[i] = sc[i] + 0.25f;

    {
        int px = l;
        const float* zp = z + (size_t)(n0 >> 12) * CHW_ + (n0 & 4095) + px;
        int key = (px >> 3) & 3;
#pragma unroll 4
        for (int i = 0; i < 32; i++) {
            int widx = w * 32 + i;
            int c0 = widx * 2;
            float v0 = zp[(size_t)c0 * HW_];
            float v1 = zp[(size_t)(c0 + 1) * HW_];
            unsigned pk = (unsigned)__half_as_ushort(__float2half_rn(v0))
                        | ((unsigned)__half_as_ushort(__float2half_rn(v1)) << 16);
            int c16 = widx >> 2, rem = widx & 3;
            zw[px * 132 + (((c16 ^ key) << 2) | rem)] = pk;
        }
    }
    __syncthreads();

    unsigned b1[2] = { 0xFFFFFFFFu, 0xFFFFFFFFu };
    unsigned b2[2] = { 0xFFFFFFFFu, 0xFFFFFFFFu };

    const unsigned short* ab = cbh + ((size_t)(w * 64 + (l & 31)) * 16 + (l >> 5) * 8);
    short rowmap = (short)((l >> 5) << 2);
    half8 pf[2][2];
#pragma unroll
    for (int i = 0; i < 2; i++) {
        const unsigned short* s = ab + (i & 15) * 16384 + (i >> 4) * 4096;
        pf[i][0] = *(const half8*)(s);
        pf[i][1] = *(const half8*)(s + 512);
    }

    int bkey = ((l & 31) >> 3) & 3;
    int prow0 = (l & 31) * 132;

    for (int chunk = 0; chunk < 4; chunk++) {
        float16 acc[2][2];
#pragma unroll
        for (int mt = 0; mt < 2; mt++)
#pragma unroll
            for (int nt = 0; nt < 2; nt++)
#pragma unroll
                for (int r = 0; r < 16; r++) acc[mt][nt][r] = 0.f;

#pragma unroll
        for (int kk = 0; kk < 16; kk++) {
            int step = chunk * 16 + kk;
            int buf = step & 1;
            half8 a0 = pf[buf][0], a1 = pf[buf][1];
            int ns = step + 2; if (ns > 63) ns = 63;
            {
                const unsigned short* s = ab + (ns & 15) * 16384 + (ns >> 4) * 4096;
                pf[buf][0] = *(const half8*)(s);
                pf[buf][1] = *(const half8*)(s + 512);
            }
            half8 bz[2];
#pragma unroll
            for (int nt = 0; nt < 2; nt++) {
                int c16 = kk * 2 + (l >> 5);
                int word = (nt * 32 * 132 + prow0) + ((c16 ^ bkey) << 2);
                bz[nt] = *(const half8*)((const char*)zw + (size_t)word * 4);
            }
            __builtin_amdgcn_s_setprio(1);
            acc[0][0] = __builtin_amdgcn_mfma_f32_32x32x16_f16(a0, bz[0], acc[0][0], 0, 0, 0);
            acc[0][1] = __builtin_amdgcn_mfma_f32_32x32x16_f16(a0, bz[1], acc[0][1], 0, 0, 0);
            acc[1][0] = __builtin_amdgcn_mfma_f32_32x32x16_f16(a1, bz[0], acc[1][0], 0, 0, 0);
            acc[1][1] = __builtin_amdgcn_mfma_f32_32x32x16_f16(a1, bz[1], acc[1][1], 0, 0, 0);
            __builtin_amdgcn_s_setprio(0);
        }

#pragma unroll
        for (int mt = 0; mt < 2; mt++)
#pragma unroll
            for (int r = 0; r < 16; r++) {
                int scode = chunk * 256 + w * 64 + mt * 32
                          + (r & 3) + ((r >> 2) << 3) + rowmap;
                float sv = scs[scode];
                unsigned emb = (unsigned)((chunk << 5) | (mt << 4) | r);
#pragma unroll
                for (int nt = 0; nt < 2; nt++) {
                    float s = fmaf(-0.001953125f, acc[mt][nt][r], sv);
                    unsigned key = (__float_as_uint(s) & 0xFFFFFF80u) | emb;
                    b2[nt] = umin_(b2[nt], umax_(b1[nt], key));
                    b1[nt] = umin_(b1[nt], key);
                }
            }
    }

#pragma unroll
    for (int nt = 0; nt < 2; nt++) {
        unsigned e1 = b1[nt] & 127u;
        float f1 = __uint_as_float(b1[nt] & 0xFFFFFF80u);
        float f2 = __uint_as_float(b2[nt] & 0xFFFFFF80u);
        int idx = (int)(e1 >> 5) * 256 + w * 64 + (int)((e1 >> 4) & 1) * 32
                + (int)(e1 & 3) + (int)(((e1 >> 2) & 3) << 3) + (int)rowmap;

        float of1 = __shfl_xor(f1, 32, 64);
        int   oi  = __shfl_xor(idx, 32, 64);
        float of2 = __shfl_xor(f2, 32, 64);
        if (of1 < f1 || (of1 == f1 && oi < idx)) {
            f2 = fminf(f1, of2); f1 = of1; idx = oi;
        } else {
            f2 = fminf(f2, of1);
        }

        if (l < 32) {
            int e = (w * 64 + nt * 32 + l) * 4;
            ex[e + 0] = f1;
            ex[e + 1] = f2;
            ((int*)ex)[e + 2] = idx;
        }
    }
    __syncthreads();
    if (t < 64) {
        float cb1 = FLT_BIG, cb2 = FLT_BIG; int cj1 = 0;
#pragma unroll
        for (int wv = 0; wv < 4; wv++) {
            int e = (wv * 64 + t) * 4;
            float nb1 = ex[e + 0];
            float nb2 = ex[e + 1];
            int   nj1 = ((int*)ex)[e + 2];
            if (nb1 < cb1 || (nb1 == cb1 && nj1 < cj1)) {
                cb2 = fminf(cb1, nb2); cb1 = nb1; cj1 = nj1;
            } else {
                cb2 = fminf(cb2, nb1);
            }
        }
        int n = n0 + t;
        s1o[n] = cb1; s2o[n] = cb2; i1o[n] = cj1;
    }
}

// ---------------------------------------------------------------------------
// Flag pass + fused szc (r15): same grid/thread<->n mapping as old szc
// (256 x 256).  sz[n] combined from rp in the baseline's exact pairwise
// tree (bit-identical values - rp complete via stream order).  Then commit
// winners / compact near-ties as before.  One launch removed.
// ---------------------------------------------------------------------------
__global__ void flag_kernel(const float* __restrict__ rp,
                            const float* __restrict__ s1, const float* __restrict__ s2,
                            const int* __restrict__ i1,
                            int* __restrict__ fidx, float* __restrict__ out_idx,
                            int* __restrict__ list, int* __restrict__ count,
                            float* __restrict__ sz) {
#pragma clang fp contract(off)
    int n = blockIdx.x * 256 + threadIdx.x;
    {
        float blk[2];
        for (int h = 0; h < 2; h++) {
            const float* b = rp + (size_t)(h * 8) * N_ + n;
            float r0 = b[0 * N_], r1 = b[1 * N_], r2 = b[2 * N_], r3 = b[3 * N_];
            float r4 = b[4 * N_], r5 = b[5 * N_], r6 = b[6 * N_], r7 = b[7 * N_];
            blk[h] = ((r0 + r1) + (r2 + r3)) + ((r4 + r5) + (r6 + r7));
        }
        sz[n] = blk[0] + blk[1];
    }
    int j = i1[n];
    fidx[n] = j;
    out_idx[n] = (float)j;
    if (s2[n] - s1[n] < GAP_T) {
        int pos = atomicAdd(count, 1);
        list[pos] = n;
    }
}

// ---------------------------------------------------------------------------
// Exact refine (r8 P=1 VERBATIM - refine is CLOSED).  It sits AT the
// aggregate L2 roofline: cnt~2400 x 1MB cbT sweep = 2.4GB / 72us ~ 33TB/s
// vs 34.5TB/s ceiling.  All four sharing structures lost more to
// registers/latency than they saved in BW: P=4 spill (r9, 126us), P=2
// scratch-pinned at VGPR=64 (r11/r12/r13, 275-278us; static access and
// launch_bounds both falsified), LDS-tiled block sharing (r14, 111us -
// no stage/compute overlap).  Do not reopen.
// ---------------------------------------------------------------------------
__global__ void refine_kernel(const float* __restrict__ z, const float* __restrict__ cbT,
                              const float* __restrict__ sz, const float* __restrict__ sc,
                              const int* __restrict__ list, const int* __restrict__ count,
                              int* __restrict__ fidx, float* __restrict__ out_idx) {
    __shared__ double zd[4][256];
    int w = threadIdx.x >> 6, l = threadIdx.x & 63;
    int cnt = *count;
    if (cnt > 65536) cnt = 65536;
    for (int ii = blockIdx.x * 4 + w; ii < cnt; ii += 8192) {
        int n = list[ii];
        const float* zp = z + (size_t)(n >> 12) * CHW_ + (n & 4095);
#pragma unroll
        for (int j = 0; j < 4; j++)
            zd[w][l * 4 + j] = (double)zp[(size_t)(l * 4 + j) * HW_];
        asm volatile("s_waitcnt lgkmcnt(0)" ::: "memory");
        double acc[16];
#pragma unroll
        for (int a = 0; a < 16; a++) acc[a] = 0.0;
        for (int c = 0; c < 256; c++) {
            double zc = zd[w][c];
            const float* cp = cbT + (size_t)c * K_ + l * 4;
#pragma unroll
            for (int it = 0; it < 4; it++) {
                float4 cv = *(const float4*)(cp + it * 256);
                acc[it * 4 + 0] += zc * (double)cv.x;
                acc[it * 4 + 1] += zc * (double)cv.y;
                acc[it * 4 + 2] += zc * (double)cv.z;
                acc[it * 4 + 3] += zc * (double)cv.w;
            }
        }
        float szv = sz[n];
        float best = FLT_BIG; int bidx = K_;
#pragma unroll
        for (int it = 0; it < 4; it++)
#pragma unroll
            for (int s = 0; s < 4; s++) {
                int k = it * 256 + l * 4 + s;
                float dotf = (float)acc[it * 4 + s];
                float dq = (szv + sc[k]) - 2.0f * dotf;
                if (dq < best || (dq == best && k < bidx)) { best = dq; bidx = k; }
            }
#pragma unroll
        for (int off = 32; off > 0; off >>= 1) {
            float ob = __shfl_xor(best, off, 64);
            int   oj = __shfl_xor(bidx, off, 64);
            if (ob < best || (ob == best && oj < bidx)) { best = ob; bidx = oj; }
        }
        if (l == 0) { fidx[n] = bidx; out_idx[n] = (float)bidx; }
        asm volatile("s_waitcnt lgkmcnt(0)" ::: "memory");
    }
}

// ---------------------------------------------------------------------------
// Gather zq -> NCHW output + loss partials (float4 version, PASSED r8)
// ---------------------------------------------------------------------------
__global__ void output_kernel(const float* __restrict__ z, const float* __restrict__ cb,
                              const int* __restrict__ fidx,
                              float* __restrict__ out0, double* __restrict__ partials) {
    __shared__ int sidx[64];
    __shared__ double red[256];
    int t = threadIdx.x;
    int blk = blockIdx.x;
    int n0 = blk * 64;
    if (t < 64) sidx[t] = fidx[n0 + t];
    __syncthreads();
    int batch = n0 >> 12, s0 = n0 & 4095;
    const float* zbase = z + (size_t)batch * CHW_ + s0;
    float* obase = out0 + (size_t)batch * CHW_ + s0;
    int ig = (t & 15) * 4;
    int cg = (t >> 4) * 4;
    const float* r0 = cb + (size_t)sidx[ig + 0] * C_;
    const float* r1 = cb + (size_t)sidx[ig + 1] * C_;
    const float* r2 = cb + (size_t)sidx[ig + 2] * C_;
    const float* r3 = cb + (size_t)sidx[ig + 3] * C_;
    double sum = 0.0;
#pragma unroll
    for (int pass = 0; pass < 4; pass++) {
        int c0 = pass * 64 + cg;
        float4 q0 = *(const float4*)(r0 + c0);
        float4 q1 = *(const float4*)(r1 + c0);
        float4 q2 = *(const float4*)(r2 + c0);
        float4 q3 = *(const float4*)(r3 + c0);
        float a0[4] = { q0.x, q0.y, q0.z, q0.w };
        float a1[4] = { q1.x, q1.y, q1.z, q1.w };
        float a2[4] = { q2.x, q2.y, q2.z, q2.w };
        float a3[4] = { q3.x, q3.y, q3.z, q3.w };
#pragma unroll
        for (int j = 0; j < 4; j++) {
            size_t off = (size_t)(c0 + j) * HW_ + ig;
            float4 zv = *(const float4*)(zbase + off);
            float4 qq;
            qq.x = a0[j]; qq.y = a1[j]; qq.z = a2[j]; qq.w = a3[j];
            *(float4*)(obase + off) = qq;
            float d0 = qq.x - zv.x, d1 = qq.y - zv.y;
            float d2 = qq.z - zv.z, d3 = qq.w - zv.w;
            sum += (double)d0 * (double)d0;
            sum += (double)d1 * (double)d1;
            sum += (double)d2 * (double)d2;
            sum += (double)d3 * (double)d3;
        }
    }
    red[t] = sum;
    __syncthreads();
    for (int s = 128; s > 0; s >>= 1) {
        if (t < s) red[t] += red[t + s];
        __syncthreads();
    }
    if (t == 0) partials[blk] = red[0];
}

__global__ void loss_kernel(const double* __restrict__ partials, float* __restrict__ out_loss) {
    __shared__ double red[256];
    int t = threadIdx.x;
    double s = 0.0;
    for (int r = t; r < 1024; r += 256) s += partials[r];
    red[t] = s;
    __syncthreads();
    for (int k = 128; k > 0; k >>= 1) {
        if (t < k) red[t] += red[t + k];
        __syncthreads();
    }
    if (t == 0) *out_loss = (float)(0.75 * red[0] / 16777216.0);
}

// ---------------------------------------------------------------------------
extern "C" void kernel_launch(void* const* d_in, const int* in_sizes, int n_in,
                              void* d_out, int out_size, void* d_ws, size_t ws_size,
                              hipStream_t stream) {
    const float* z  = (const float*)d_in[0];
    const float* cb = (const float*)d_in[1];

    float* out0     = (float*)d_out;
    float* out_idx  = out0 + (size_t)16777216;
    float* out_loss = out0 + (size_t)16842752;

    char* w = (char*)d_ws;
    double* partials = (double*)w;                       //       0 .. 8192
    float*  sc   = (float*)(w + 8192);                   //    8192 .. 12288
    float*  sz   = (float*)(w + 12288);                  //   12288 .. 274432
    float*  s1   = (float*)(w + 274432);
    float*  s2   = (float*)(w + 536576);
    int*    i1   = (int*)  (w + 798720);
    int*    fidx = (int*)  (w + 1060864);
    int*    count= (int*)  (w + 1323008);
    int*    list = (int*)  (w + 1323264);                // 256 KB
    unsigned short* cbh = (unsigned short*)(w + 1585408);// 512 KB
    float*  cbT  = (float*)(w + 2109952);                // 1 MB -> ends 3158528
    float*  rp   = (float*)(w + 3158528);                // 4 MB sz partials -> ends 7352832

    hipMemsetAsync(count, 0, 4, stream);
    szp_kernel   <<<4096, 256, 0, stream>>>(z, rp);
    sc_kernel    <<<4,    256, 0, stream>>>(cb, sc);
    cbh_prep     <<<1024, 256, 0, stream>>>(cb, cbh);
    cbT_prep     <<<64,   256, 0, stream>>>(cb, cbT);
    score_kernel <<<1024, 256, 0, stream>>>(z, cbh, sc, s1, s2, i1);
    flag_kernel  <<<256,  256, 0, stream>>>(rp, s1, s2, i1, fidx, out_idx, list, count, sz);
    refine_kernel<<<2048, 256, 0, stream>>>(z, cbT, sz, sc, list, count, fidx, out_idx);
    output_kernel<<<1024, 256, 0, stream>>>(z, cb, fidx, out0, partials);
    loss_kernel  <<<1,    256, 0, stream>>>(partials, out_loss);
}

// Round 16
// 277.011 us; speedup vs baseline: 1.7734x; 1.0083x over previous
//
#include <hip/hip_runtime.h>
#include <hip/hip_fp16.h>

#define B_    16
#define C_    256
#define HW_   4096
#define CHW_  1048576
#define N_    65536
#define K_    1024
#define FLT_BIG 3.402823466e38f
#define GAP_T  1.2e-4f   // ref fp32-quant floor 6.1e-5 + 6sigma fp16 score err ~3.1e-5 + key-pack 8e-6 + margin

typedef _Float16 half8 __attribute__((ext_vector_type(8)));
typedef float   float16 __attribute__((ext_vector_type(16)));

__device__ __forceinline__ unsigned umin_(unsigned a, unsigned b) { return a < b ? a : b; }
__device__ __forceinline__ unsigned umax_(unsigned a, unsigned b) { return a > b ? a : b; }

// ---------------------------------------------------------------------------
// s_z partial pass (PASSED r7/r15): thread owns ONE (h,j) chain of pixel n,
// sequential i-order.  Combine (numpy-pairwise exact) fused into flag.
// ---------------------------------------------------------------------------
__global__ void szp_kernel(const float* __restrict__ z, float* __restrict__ rp) {
#pragma clang fp contract(off)
    int hj = blockIdx.x >> 8;              // 0..15  (h = hj>>3, j = hj&7)
    int bx = blockIdx.x & 255;
    int n  = bx * 256 + threadIdx.x;
    int h = hj >> 3, j = hj & 7;
    const float* p = z + (size_t)(n >> 12) * CHW_ + (n & 4095)
                       + (size_t)(h * 128 + j) * HW_;
    float v = p[0];
    float r = v * v;
    for (int s = 1; s < 16; s++) {
        float u = p[(size_t)(s * 8) * HW_];
        r += u * u;
    }
    rp[(size_t)hj * N_ + n] = r;
}

// ---------------------------------------------------------------------------
// Merged prep (r16): sc + cbh_prep + cbT_prep in one launch (all read cb,
// disjoint outputs; per-branch code identical to the r15-passing kernels).
// Grid 1092 blocks x 256 thr: [0,1024)=cbh, [1024,1088)=cbT, [1088,1092)=sc.
// ---------------------------------------------------------------------------
__global__ void prep_kernel(const float* __restrict__ cb,
                            unsigned short* __restrict__ cbh,
                            float* __restrict__ cbT,
                            float* __restrict__ sc) {
    int b = blockIdx.x;
    if (b < 1024) {
        // cbh: codebook -> fp16 (x1024 exact scale), A-fragment image
        int k = b, c = threadIdx.x;
        float v = cb[(size_t)k * C_ + c] * 1024.0f;
        __half hv = __float2half_rn(v);
        size_t F = ((size_t)(c >> 4) * 1024 + k) * 16 + ((c >> 3) & 1) * 8 + (c & 7);
        cbh[F] = __half_as_ushort(hv);
    } else if (b < 1088) {
        // cbT[c][k] = cb[k][c], LDS-tiled 64x64 (PASSED r15)
        __shared__ float tile[64][65];
        int bb = b - 1024;
        int bx = bb & 15;                  // k-tile 0..15
        int by = bb >> 4;                  // c-tile 0..3
        int tc = threadIdx.x & 63, tr = threadIdx.x >> 6;
#pragma unroll
        for (int i = 0; i < 16; i++) {
            int k = tr + i * 4;
            tile[k][tc] = cb[(size_t)(bx * 64 + k) * C_ + by * 64 + tc];
        }
        __syncthreads();
#pragma unroll
        for (int i = 0; i < 16; i++) {
            int cc = tr + i * 4;
            cbT[(size_t)(by * 64 + cc) * K_ + bx * 64 + tc] = tile[tc][cc];
        }
    } else {
        // s_c[k] numpy pairwise order (PASSED r2/r4)
#pragma clang fp contract(off)
        int k = (b - 1088) * 256 + threadIdx.x;
        const float* p0 = cb + (size_t)k * C_;
        float blk[2];
        for (int h = 0; h < 2; h++) {
            const float* p = p0 + h * 128;
            float r[8];
#pragma unroll
            for (int j = 0; j < 8; j++) { float v = p[j]; r[j] = v * v; }
            for (int i = 8; i < 128; i += 8) {
#pragma unroll
                for (int j = 0; j < 8; j++) { float v = p[i + j]; r[j] += v * v; }
            }
            blk[h] = ((r[0] + r[1]) + (r[2] + r[3])) + ((r[4] + r[5]) + (r[6] + r[7]));
        }
        sc[k] = blk[0] + blk[1];
    }
}

// ---------------------------------------------------------------------------
// fp16 MFMA score kernel.  Block = 64 pixels, 256 thr (4 waves).
// (structure PASSED r6/r7/r8/r15; setprio T5 added r8)
// NOTE: LDS deliberately 41984 B (3 blocks/CU).  All 40960-B (4 blocks/CU)
// variants failed idx verification 3-for-3 (r3/r4/r5) with identical
// arithmetic - do not retry without a mechanism.
// r16: A-prefetch depth 2 -> 3 (pf[3][2], +8 VGPR -> ~168 <= 170 cap for
// 3 waves/SIMD).  Latency model: depth-2 covered ~100cy of ~200cy L2 hit
// -> ~100cy stall/step -> MfmaUtil 16.8% (matches 32cy MFMA / 150cy step).
// Depth-3 covers ~150cy.  BOTH chunk+kk loops fully unrolled so step%3 is
// compile-time constant (rule #20: no runtime-indexed register arrays).
// Arithmetic unchanged.
// ---------------------------------------------------------------------------
__global__ __launch_bounds__(256, 4)
void score_kernel(const float* __restrict__ z, const unsigned short* __restrict__ cbh,
                  const float* __restrict__ sc,
                  float* __restrict__ s1o, float* __restrict__ s2o,
                  int* __restrict__ i1o) {
    __shared__ __align__(16) int zw[64 * 132];   // 33792 B
    __shared__ float scs[1024];                  // 4 KB
    __shared__ float ex[4 * 64 * 4];             // 4 KB

    int t = threadIdx.x;
    int w = t >> 6, l = t & 63;
    int n0 = blockIdx.x * 64;

    for (int i = t; i < 1024; i += 256) scs[i] = sc[i] + 0.25f;

    {
        int px = l;
        const float* zp = z + (size_t)(n0 >> 12) * CHW_ + (n0 & 4095) + px;
        int key = (px >> 3) & 3;
#pragma unroll 4
        for (int i = 0; i < 32; i++) {
            int widx = w * 32 + i;
            int c0 = widx * 2;
            float v0 = zp[(size_t)c0 * HW_];
            float v1 = zp[(size_t)(c0 + 1) * HW_];
            unsigned pk = (unsigned)__half_as_ushort(__float2half_rn(v0))
                        | ((unsigned)__half_as_ushort(__float2half_rn(v1)) << 16);
            int c16 = widx >> 2, rem = widx & 3;
            zw[px * 132 + (((c16 ^ key) << 2) | rem)] = pk;
        }
    }
    __syncthreads();

    unsigned b1[2] = { 0xFFFFFFFFu, 0xFFFFFFFFu };
    unsigned b2[2] = { 0xFFFFFFFFu, 0xFFFFFFFFu };

    const unsigned short* ab = cbh + ((size_t)(w * 64 + (l & 31)) * 16 + (l >> 5) * 8);
    short rowmap = (short)((l >> 5) << 2);
    half8 pf[3][2];
#pragma unroll
    for (int i = 0; i < 3; i++) {
        const unsigned short* s = ab + (i & 15) * 16384 + (i >> 4) * 4096;
        pf[i][0] = *(const half8*)(s);
        pf[i][1] = *(const half8*)(s + 512);
    }

    int bkey = ((l & 31) >> 3) & 3;
    int prow0 = (l & 31) * 132;

#pragma unroll
    for (int chunk = 0; chunk < 4; chunk++) {
        float16 acc[2][2];
#pragma unroll
        for (int mt = 0; mt < 2; mt++)
#pragma unroll
            for (int nt = 0; nt < 2; nt++)
#pragma unroll
                for (int r = 0; r < 16; r++) acc[mt][nt][r] = 0.f;

#pragma unroll
        for (int kk = 0; kk < 16; kk++) {
            int step = chunk * 16 + kk;
            int buf = step % 3;
            half8 a0 = pf[buf][0], a1 = pf[buf][1];
            int ns = step + 3; if (ns > 63) ns = 63;
            {
                const unsigned short* s = ab + (ns & 15) * 16384 + (ns >> 4) * 4096;
                pf[buf][0] = *(const half8*)(s);
                pf[buf][1] = *(const half8*)(s + 512);
            }
            half8 bz[2];
#pragma unroll
            for (int nt = 0; nt < 2; nt++) {
                int c16 = kk * 2 + (l >> 5);
                int word = (nt * 32 * 132 + prow0) + ((c16 ^ bkey) << 2);
                bz[nt] = *(const half8*)((const char*)zw + (size_t)word * 4);
            }
            __builtin_amdgcn_s_setprio(1);
            acc[0][0] = __builtin_amdgcn_mfma_f32_32x32x16_f16(a0, bz[0], acc[0][0], 0, 0, 0);
            acc[0][1] = __builtin_amdgcn_mfma_f32_32x32x16_f16(a0, bz[1], acc[0][1], 0, 0, 0);
            acc[1][0] = __builtin_amdgcn_mfma_f32_32x32x16_f16(a1, bz[0], acc[1][0], 0, 0, 0);
            acc[1][1] = __builtin_amdgcn_mfma_f32_32x32x16_f16(a1, bz[1], acc[1][1], 0, 0, 0);
            __builtin_amdgcn_s_setprio(0);
        }

#pragma unroll
        for (int mt = 0; mt < 2; mt++)
#pragma unroll
            for (int r = 0; r < 16; r++) {
                int scode = chunk * 256 + w * 64 + mt * 32
                          + (r & 3) + ((r >> 2) << 3) + rowmap;
                float sv = scs[scode];
                unsigned emb = (unsigned)((chunk << 5) | (mt << 4) | r);
#pragma unroll
                for (int nt = 0; nt < 2; nt++) {
                    float s = fmaf(-0.001953125f, acc[mt][nt][r], sv);
                    unsigned key = (__float_as_uint(s) & 0xFFFFFF80u) | emb;
                    b2[nt] = umin_(b2[nt], umax_(b1[nt], key));
                    b1[nt] = umin_(b1[nt], key);
                }
            }
    }

#pragma unroll
    for (int nt = 0; nt < 2; nt++) {
        unsigned e1 = b1[nt] & 127u;
        float f1 = __uint_as_float(b1[nt] & 0xFFFFFF80u);
        float f2 = __uint_as_float(b2[nt] & 0xFFFFFF80u);
        int idx = (int)(e1 >> 5) * 256 + w * 64 + (int)((e1 >> 4) & 1) * 32
                + (int)(e1 & 3) + (int)(((e1 >> 2) & 3) << 3) + (int)rowmap;

        float of1 = __shfl_xor(f1, 32, 64);
        int   oi  = __shfl_xor(idx, 32, 64);
        float of2 = __shfl_xor(f2, 32, 64);
        if (of1 < f1 || (of1 == f1 && oi < idx)) {
            f2 = fminf(f1, of2); f1 = of1; idx = oi;
        } else {
            f2 = fminf(f2, of1);
        }

        if (l < 32) {
            int e = (w * 64 + nt * 32 + l) * 4;
            ex[e + 0] = f1;
            ex[e + 1] = f2;
            ((int*)ex)[e + 2] = idx;
        }
    }
    __syncthreads();
    if (t < 64) {
        float cb1 = FLT_BIG, cb2 = FLT_BIG; int cj1 = 0;
#pragma unroll
        for (int wv = 0; wv < 4; wv++) {
            int e = (wv * 64 + t) * 4;
            float nb1 = ex[e + 0];
            float nb2 = ex[e + 1];
            int   nj1 = ((int*)ex)[e + 2];
            if (nb1 < cb1 || (nb1 == cb1 && nj1 < cj1)) {
                cb2 = fminf(cb1, nb2); cb1 = nb1; cj1 = nj1;
            } else {
                cb2 = fminf(cb2, nb1);
            }
        }
        int n = n0 + t;
        s1o[n] = cb1; s2o[n] = cb2; i1o[n] = cj1;
    }
}

// ---------------------------------------------------------------------------
// Flag pass + fused szc (PASSED r15): sz[n] combined from rp in the exact
// pairwise tree; then commit winners / compact near-ties.
// ---------------------------------------------------------------------------
__global__ void flag_kernel(const float* __restrict__ rp,
                            const float* __restrict__ s1, const float* __restrict__ s2,
                            const int* __restrict__ i1,
                            int* __restrict__ fidx, float* __restrict__ out_idx,
                            int* __restrict__ list, int* __restrict__ count,
                            float* __restrict__ sz) {
#pragma clang fp contract(off)
    int n = blockIdx.x * 256 + threadIdx.x;
    {
        float blk[2];
        for (int h = 0; h < 2; h++) {
            const float* b = rp + (size_t)(h * 8) * N_ + n;
            float r0 = b[0 * N_], r1 = b[1 * N_], r2 = b[2 * N_], r3 = b[3 * N_];
            float r4 = b[4 * N_], r5 = b[5 * N_], r6 = b[6 * N_], r7 = b[7 * N_];
            blk[h] = ((r0 + r1) + (r2 + r3)) + ((r4 + r5) + (r6 + r7));
        }
        sz[n] = blk[0] + blk[1];
    }
    int j = i1[n];
    fidx[n] = j;
    out_idx[n] = (float)j;
    if (s2[n] - s1[n] < GAP_T) {
        int pos = atomicAdd(count, 1);
        list[pos] = n;
    }
}

// ---------------------------------------------------------------------------
// Exact refine (r8 P=1 VERBATIM - refine is CLOSED, at its L2 roofline:
// cnt~2400 x 1MB cbT sweep = 2.4GB / 72us ~ 33TB/s vs 34.5TB/s ceiling).
// Sharing structures all lost more to registers/latency than BW saved:
// r9 P=4 spill 126us; r11/r12/r13 P=2 scratch-pinned 275-278us;
// r14 LDS-tiled 111us.  Do not reopen.
// ---------------------------------------------------------------------------
__global__ void refine_kernel(const float* __restrict__ z, const float* __restrict__ cbT,
                              const float* __restrict__ sz, const float* __restrict__ sc,
                              const int* __restrict__ list, const int* __restrict__ count,
                              int* __restrict__ fidx, float* __restrict__ out_idx) {
    __shared__ double zd[4][256];
    int w = threadIdx.x >> 6, l = threadIdx.x & 63;
    int cnt = *count;
    if (cnt > 65536) cnt = 65536;
    for (int ii = blockIdx.x * 4 + w; ii < cnt; ii += 8192) {
        int n = list[ii];
        const float* zp = z + (size_t)(n >> 12) * CHW_ + (n & 4095);
#pragma unroll
        for (int j = 0; j < 4; j++)
            zd[w][l * 4 + j] = (double)zp[(size_t)(l * 4 + j) * HW_];
        asm volatile("s_waitcnt lgkmcnt(0)" ::: "memory");
        double acc[16];
#pragma unroll
        for (int a = 0; a < 16; a++) acc[a] = 0.0;
        for (int c = 0; c < 256; c++) {
            double zc = zd[w][c];
            const float* cp = cbT + (size_t)c * K_ + l * 4;
#pragma unroll
            for (int it = 0; it < 4; it++) {
                float4 cv = *(const float4*)(cp + it * 256);
                acc[it * 4 + 0] += zc * (double)cv.x;
                acc[it * 4 + 1] += zc * (double)cv.y;
                acc[it * 4 + 2] += zc * (double)cv.z;
                acc[it * 4 + 3] += zc * (double)cv.w;
            }
        }
        float szv = sz[n];
        float best = FLT_BIG; int bidx = K_;
#pragma unroll
        for (int it = 0; it < 4; it++)
#pragma unroll
            for (int s = 0; s < 4; s++) {
                int k = it * 256 + l * 4 + s;
                float dotf = (float)acc[it * 4 + s];
                float dq = (szv + sc[k]) - 2.0f * dotf;
                if (dq < best || (dq == best && k < bidx)) { best = dq; bidx = k; }
            }
#pragma unroll
        for (int off = 32; off > 0; off >>= 1) {
            float ob = __shfl_xor(best, off, 64);
            int   oj = __shfl_xor(bidx, off, 64);
            if (ob < best || (ob == best && oj < bidx)) { best = ob; bidx = oj; }
        }
        if (l == 0) { fidx[n] = bidx; out_idx[n] = (float)bidx; }
        asm volatile("s_waitcnt lgkmcnt(0)" ::: "memory");
    }
}

// ---------------------------------------------------------------------------
// Gather zq -> NCHW output + loss partials (float4 version, PASSED r8)
// ---------------------------------------------------------------------------
__global__ void output_kernel(const float* __restrict__ z, const float* __restrict__ cb,
                              const int* __restrict__ fidx,
                              float* __restrict__ out0, double* __restrict__ partials) {
    __shared__ int sidx[64];
    __shared__ double red[256];
    int t = threadIdx.x;
    int blk = blockIdx.x;
    int n0 = blk * 64;
    if (t < 64) sidx[t] = fidx[n0 + t];
    __syncthreads();
    int batch = n0 >> 12, s0 = n0 & 4095;
    const float* zbase = z + (size_t)batch * CHW_ + s0;
    float* obase = out0 + (size_t)batch * CHW_ + s0;
    int ig = (t & 15) * 4;
    int cg = (t >> 4) * 4;
    const float* r0 = cb + (size_t)sidx[ig + 0] * C_;
    const float* r1 = cb + (size_t)sidx[ig + 1] * C_;
    const float* r2 = cb + (size_t)sidx[ig + 2] * C_;
    const float* r3 = cb + (size_t)sidx[ig + 3] * C_;
    double sum = 0.0;
#pragma unroll
    for (int pass = 0; pass < 4; pass++) {
        int c0 = pass * 64 + cg;
        float4 q0 = *(const float4*)(r0 + c0);
        float4 q1 = *(const float4*)(r1 + c0);
        float4 q2 = *(const float4*)(r2 + c0);
        float4 q3 = *(const float4*)(r3 + c0);
        float a0[4] = { q0.x, q0.y, q0.z, q0.w };
        float a1[4] = { q1.x, q1.y, q1.z, q1.w };
        float a2[4] = { q2.x, q2.y, q2.z, q2.w };
        float a3[4] = { q3.x, q3.y, q3.z, q3.w };
#pragma unroll
        for (int j = 0; j < 4; j++) {
            size_t off = (size_t)(c0 + j) * HW_ + ig;
            float4 zv = *(const float4*)(zbase + off);
            float4 qq;
            qq.x = a0[j]; qq.y = a1[j]; qq.z = a2[j]; qq.w = a3[j];
            *(float4*)(obase + off) = qq;
            float d0 = qq.x - zv.x, d1 = qq.y - zv.y;
            float d2 = qq.z - zv.z, d3 = qq.w - zv.w;
            sum += (double)d0 * (double)d0;
            sum += (double)d1 * (double)d1;
            sum += (double)d2 * (double)d2;
            sum += (double)d3 * (double)d3;
        }
    }
    red[t] = sum;
    __syncthreads();
    for (int s = 128; s > 0; s >>= 1) {
        if (t < s) red[t] += red[t + s];
        __syncthreads();
    }
    if (t == 0) partials[blk] = red[0];
}

__global__ void loss_kernel(const double* __restrict__ partials, float* __restrict__ out_loss) {
    __shared__ double red[256];
    int t = threadIdx.x;
    double s = 0.0;
    for (int r = t; r < 1024; r += 256) s += partials[r];
    red[t] = s;
    __syncthreads();
    for (int k = 128; k > 0; k >>= 1) {
        if (t < k) red[t] += red[t + k];
        __syncthreads();
    }
    if (t == 0) *out_loss = (float)(0.75 * red[0] / 16777216.0);
}

// ---------------------------------------------------------------------------
extern "C" void kernel_launch(void* const* d_in, const int* in_sizes, int n_in,
                              void* d_out, int out_size, void* d_ws, size_t ws_size,
                              hipStream_t stream) {
    const float* z  = (const float*)d_in[0];
    const float* cb = (const float*)d_in[1];

    float* out0     = (float*)d_out;
    float* out_idx  = out0 + (size_t)16777216;
    float* out_loss = out0 + (size_t)16842752;

    char* w = (char*)d_ws;
    double* partials = (double*)w;                       //       0 .. 8192
    float*  sc   = (float*)(w + 8192);                   //    8192 .. 12288
    float*  sz   = (float*)(w + 12288);                  //   12288 .. 274432
    float*  s1   = (float*)(w + 274432);
    float*  s2   = (float*)(w + 536576);
    int*    i1   = (int*)  (w + 798720);
    int*    fidx = (int*)  (w + 1060864);
    int*    count= (int*)  (w + 1323008);
    int*    list = (int*)  (w + 1323264);                // 256 KB
    unsigned short* cbh = (unsigned short*)(w + 1585408);// 512 KB
    float*  cbT  = (float*)(w + 2109952);                // 1 MB -> ends 3158528
    float*  rp   = (float*)(w + 3158528);                // 4 MB sz partials -> ends 7352832

    hipMemsetAsync(count, 0, 4, stream);
    szp_kernel   <<<4096, 256, 0, stream>>>(z, rp);
    prep_kernel  <<<1092, 256, 0, stream>>>(cb, cbh, cbT, sc);
    score_kernel <<<1024, 256, 0, stream>>>(z, cbh, sc, s1, s2, i1);
    flag_kernel  <<<256,  256, 0, stream>>>(rp, s1, s2, i1, fidx, out_idx, list, count, sz);
    refine_kernel<<<2048, 256, 0, stream>>>(z, cbT, sz, sc, list, count, fidx, out_idx);
    output_kernel<<<1024, 256, 0, stream>>>(z, cb, fidx, out0, partials);
    loss_kernel  <<<1,    256, 0, stream>>>(partials, out_loss);
}

// Round 17
// 264.116 us; speedup vs baseline: 1.8599x; 1.0488x over previous
//
#include <hip/hip_runtime.h>
#include <hip/hip_fp16.h>

#define B_    16
#define C_    256
#define HW_   4096
#define CHW_  1048576
#define N_    65536
#define K_    1024
#define FLT_BIG 3.402823466e38f
#define GAP_T  1.2e-4f   // ref fp32-quant floor 6.1e-5 + 6sigma fp16 score err ~3.1e-5 + key-pack 8e-6 + margin

typedef _Float16 half8 __attribute__((ext_vector_type(8)));
typedef float   float16 __attribute__((ext_vector_type(16)));

__device__ __forceinline__ unsigned umin_(unsigned a, unsigned b) { return a < b ? a : b; }
__device__ __forceinline__ unsigned umax_(unsigned a, unsigned b) { return a > b ? a : b; }

// ---------------------------------------------------------------------------
// Merged pre-pass (r17): szp + cbh + cbT + sc in ONE launch.  All branches
// byte-identical to r15/r16-passing kernels; szp and prep are independent.
// Grid 5188 x 256: [0,4096)=szp, [4096,5120)=cbh, [5120,5184)=cbT,
// [5184,5188)=sc.
// ---------------------------------------------------------------------------
__global__ void pre_kernel(const float* __restrict__ z, const float* __restrict__ cb,
                           float* __restrict__ rp, unsigned short* __restrict__ cbh,
                           float* __restrict__ cbT, float* __restrict__ sc) {
    __shared__ float tile[64][65];
    int b = blockIdx.x;
    if (b < 4096) {
        // s_z partial (PASSED r7/r15): thread owns ONE (h,j) chain, seq i-order
#pragma clang fp contract(off)
        int hj = b >> 8;                   // 0..15  (h = hj>>3, j = hj&7)
        int bx = b & 255;
        int n  = bx * 256 + threadIdx.x;
        int h = hj >> 3, j = hj & 7;
        const float* p = z + (size_t)(n >> 12) * CHW_ + (n & 4095)
                           + (size_t)(h * 128 + j) * HW_;
        float v = p[0];
        float r = v * v;
        for (int s = 1; s < 16; s++) {
            float u = p[(size_t)(s * 8) * HW_];
            r += u * u;
        }
        rp[(size_t)hj * N_ + n] = r;
    } else if (b < 5120) {
        // cbh: codebook -> fp16 (x1024 exact scale), A-fragment image
        int k = b - 4096, c = threadIdx.x;
        float v = cb[(size_t)k * C_ + c] * 1024.0f;
        __half hv = __float2half_rn(v);
        size_t F = ((size_t)(c >> 4) * 1024 + k) * 16 + ((c >> 3) & 1) * 8 + (c & 7);
        cbh[F] = __half_as_ushort(hv);
    } else if (b < 5184) {
        // cbT[c][k] = cb[k][c], LDS-tiled 64x64 (PASSED r15)
        int bb = b - 5120;
        int bx = bb & 15;                  // k-tile 0..15
        int by = bb >> 4;                  // c-tile 0..3
        int tc = threadIdx.x & 63, tr = threadIdx.x >> 6;
#pragma unroll
        for (int i = 0; i < 16; i++) {
            int k = tr + i * 4;
            tile[k][tc] = cb[(size_t)(bx * 64 + k) * C_ + by * 64 + tc];
        }
        __syncthreads();
#pragma unroll
        for (int i = 0; i < 16; i++) {
            int cc = tr + i * 4;
            cbT[(size_t)(by * 64 + cc) * K_ + bx * 64 + tc] = tile[tc][cc];
        }
    } else {
        // s_c[k] numpy pairwise order (PASSED r2/r4)
#pragma clang fp contract(off)
        int k = (b - 5184) * 256 + threadIdx.x;
        const float* p0 = cb + (size_t)k * C_;
        float blk[2];
        for (int h = 0; h < 2; h++) {
            const float* p = p0 + h * 128;
            float r[8];
#pragma unroll
            for (int j = 0; j < 8; j++) { float v = p[j]; r[j] = v * v; }
            for (int i = 8; i < 128; i += 8) {
#pragma unroll
                for (int j = 0; j < 8; j++) { float v = p[i + j]; r[j] += v * v; }
            }
            blk[h] = ((r[0] + r[1]) + (r[2] + r[3])) + ((r[4] + r[5]) + (r[6] + r[7]));
        }
        sc[k] = blk[0] + blk[1];
    }
}

// ---------------------------------------------------------------------------
// fp16 MFMA score kernel.  Block = 64 pixels, 256 thr (4 waves).
// (structure PASSED r6/r7/r8/r15/r16; setprio T5 r8; depth-3 prefetch r16)
// NOTE: LDS deliberately 41984 B (3 blocks/CU).  All 40960-B (4 blocks/CU)
// variants failed idx verification 3-for-3 (r3/r4/r5) with identical
// arithmetic - do not retry without a mechanism.  This kernel keeps LDS at
// exactly 41984 (zw+scs+ex unchanged).
// r17: flag+szc FUSED into the t<64 epilogue (body = r15/r16-verified flag
// kernel verbatim; fp contract(off) scoped on the sz combine; rp complete
// via stream order).  Curse audit: r5 failed with flag UNfused at LDS
// 40960 -> the failing covariate was LDS size, not fusion.  s1/s2/i1
// round-trip (768KB) and one launch removed.
// ---------------------------------------------------------------------------
__global__ __launch_bounds__(256, 4)
void score_kernel(const float* __restrict__ z, const unsigned short* __restrict__ cbh,
                  const float* __restrict__ sc, const float* __restrict__ rp,
                  int* __restrict__ fidx, float* __restrict__ out_idx,
                  int* __restrict__ list, int* __restrict__ count,
                  float* __restrict__ sz) {
    __shared__ __align__(16) int zw[64 * 132];   // 33792 B
    __shared__ float scs[1024];                  // 4 KB
    __shared__ float ex[4 * 64 * 4];             // 4 KB

    int t = threadIdx.x;
    int w = t >> 6, l = t & 63;
    int n0 = blockIdx.x * 64;

    for (int i = t; i < 1024; i += 256) scs[i] = sc[i] + 0.25f;

    {
        int px = l;
        const float* zp = z + (size_t)(n0 >> 12) * CHW_ + (n0 & 4095) + px;
        int key = (px >> 3) & 3;
#pragma unroll 4
        for (int i = 0; i < 32; i++) {
            int widx = w * 32 + i;
            int c0 = widx * 2;
            float v0 = zp[(size_t)c0 * HW_];
            float v1 = zp[(size_t)(c0 + 1) * HW_];
            unsigned pk = (unsigned)__half_as_ushort(__float2half_rn(v0))
                        | ((unsigned)__half_as_ushort(__float2half_rn(v1)) << 16);
            int c16 = widx >> 2, rem = widx & 3;
            zw[px * 132 + (((c16 ^ key) << 2) | rem)] = pk;
        }
    }
    __syncthreads();

    unsigned b1[2] = { 0xFFFFFFFFu, 0xFFFFFFFFu };
    unsigned b2[2] = { 0xFFFFFFFFu, 0xFFFFFFFFu };

    const unsigned short* ab = cbh + ((size_t)(w * 64 + (l & 31)) * 16 + (l >> 5) * 8);
    short rowmap = (short)((l >> 5) << 2);
    half8 pf[3][2];
#pragma unroll
    for (int i = 0; i < 3; i++) {
        const unsigned short* s = ab + (i & 15) * 16384 + (i >> 4) * 4096;
        pf[i][0] = *(const half8*)(s);
        pf[i][1] = *(const half8*)(s + 512);
    }

    int bkey = ((l & 31) >> 3) & 3;
    int prow0 = (l & 31) * 132;

#pragma unroll
    for (int chunk = 0; chunk < 4; chunk++) {
        float16 acc[2][2];
#pragma unroll
        for (int mt = 0; mt < 2; mt++)
#pragma unroll
            for (int nt = 0; nt < 2; nt++)
#pragma unroll
                for (int r = 0; r < 16; r++) acc[mt][nt][r] = 0.f;

#pragma unroll
        for (int kk = 0; kk < 16; kk++) {
            int step = chunk * 16 + kk;
            int buf = step % 3;
            half8 a0 = pf[buf][0], a1 = pf[buf][1];
            int ns = step + 3; if (ns > 63) ns = 63;
            {
                const unsigned short* s = ab + (ns & 15) * 16384 + (ns >> 4) * 4096;
                pf[buf][0] = *(const half8*)(s);
                pf[buf][1] = *(const half8*)(s + 512);
            }
            half8 bz[2];
#pragma unroll
            for (int nt = 0; nt < 2; nt++) {
                int c16 = kk * 2 + (l >> 5);
                int word = (nt * 32 * 132 + prow0) + ((c16 ^ bkey) << 2);
                bz[nt] = *(const half8*)((const char*)zw + (size_t)word * 4);
            }
            __builtin_amdgcn_s_setprio(1);
            acc[0][0] = __builtin_amdgcn_mfma_f32_32x32x16_f16(a0, bz[0], acc[0][0], 0, 0, 0);
            acc[0][1] = __builtin_amdgcn_mfma_f32_32x32x16_f16(a0, bz[1], acc[0][1], 0, 0, 0);
            acc[1][0] = __builtin_amdgcn_mfma_f32_32x32x16_f16(a1, bz[0], acc[1][0], 0, 0, 0);
            acc[1][1] = __builtin_amdgcn_mfma_f32_32x32x16_f16(a1, bz[1], acc[1][1], 0, 0, 0);
            __builtin_amdgcn_s_setprio(0);
        }

#pragma unroll
        for (int mt = 0; mt < 2; mt++)
#pragma unroll
            for (int r = 0; r < 16; r++) {
                int scode = chunk * 256 + w * 64 + mt * 32
                          + (r & 3) + ((r >> 2) << 3) + rowmap;
                float sv = scs[scode];
                unsigned emb = (unsigned)((chunk << 5) | (mt << 4) | r);
#pragma unroll
                for (int nt = 0; nt < 2; nt++) {
                    float s = fmaf(-0.001953125f, acc[mt][nt][r], sv);
                    unsigned key = (__float_as_uint(s) & 0xFFFFFF80u) | emb;
                    b2[nt] = umin_(b2[nt], umax_(b1[nt], key));
                    b1[nt] = umin_(b1[nt], key);
                }
            }
    }

#pragma unroll
    for (int nt = 0; nt < 2; nt++) {
        unsigned e1 = b1[nt] & 127u;
        float f1 = __uint_as_float(b1[nt] & 0xFFFFFF80u);
        float f2 = __uint_as_float(b2[nt] & 0xFFFFFF80u);
        int idx = (int)(e1 >> 5) * 256 + w * 64 + (int)((e1 >> 4) & 1) * 32
                + (int)(e1 & 3) + (int)(((e1 >> 2) & 3) << 3) + (int)rowmap;

        float of1 = __shfl_xor(f1, 32, 64);
        int   oi  = __shfl_xor(idx, 32, 64);
        float of2 = __shfl_xor(f2, 32, 64);
        if (of1 < f1 || (of1 == f1 && oi < idx)) {
            f2 = fminf(f1, of2); f1 = of1; idx = oi;
        } else {
            f2 = fminf(f2, of1);
        }

        if (l < 32) {
            int e = (w * 64 + nt * 32 + l) * 4;
            ex[e + 0] = f1;
            ex[e + 1] = f2;
            ((int*)ex)[e + 2] = idx;
        }
    }
    __syncthreads();
    if (t < 64) {
        float cb1 = FLT_BIG, cb2 = FLT_BIG; int cj1 = 0;
#pragma unroll
        for (int wv = 0; wv < 4; wv++) {
            int e = (wv * 64 + t) * 4;
            float nb1 = ex[e + 0];
            float nb2 = ex[e + 1];
            int   nj1 = ((int*)ex)[e + 2];
            if (nb1 < cb1 || (nb1 == cb1 && nj1 < cj1)) {
                cb2 = fminf(cb1, nb2); cb1 = nb1; cj1 = nj1;
            } else {
                cb2 = fminf(cb2, nb1);
            }
        }
        int n = n0 + t;
        // fused szc (r15/r16-verified flag body, verbatim; exact pairwise tree)
        {
#pragma clang fp contract(off)
            float blk[2];
            for (int h = 0; h < 2; h++) {
                const float* bp = rp + (size_t)(h * 8) * N_ + n;
                float r0 = bp[0 * N_], r1 = bp[1 * N_], r2 = bp[2 * N_], r3 = bp[3 * N_];
                float r4 = bp[4 * N_], r5 = bp[5 * N_], r6 = bp[6 * N_], r7 = bp[7 * N_];
                blk[h] = ((r0 + r1) + (r2 + r3)) + ((r4 + r5) + (r6 + r7));
            }
            sz[n] = blk[0] + blk[1];
        }
        // fused flag: commit winner; compact near-ties
        fidx[n] = cj1;
        out_idx[n] = (float)cj1;
        if (cb2 - cb1 < GAP_T) {
            int pos = atomicAdd(count, 1);
            list[pos] = n;
        }
    }
}

// ---------------------------------------------------------------------------
// Exact refine (r8 P=1 VERBATIM - refine is CLOSED, at its L2 roofline:
// cnt~2400 x 1MB cbT sweep = 2.4GB / 72us ~ 33TB/s vs 34.5TB/s ceiling).
// Sharing structures all lost more to registers/latency than BW saved:
// r9 P=4 spill 126us; r11/r12/r13 P=2 scratch-pinned 275-278us;
// r14 LDS-tiled 111us.  Do not reopen.
// ---------------------------------------------------------------------------
__global__ void refine_kernel(const float* __restrict__ z, const float* __restrict__ cbT,
                              const float* __restrict__ sz, const float* __restrict__ sc,
                              const int* __restrict__ list, const int* __restrict__ count,
                              int* __restrict__ fidx, float* __restrict__ out_idx) {
    __shared__ double zd[4][256];
    int w = threadIdx.x >> 6, l = threadIdx.x & 63;
    int cnt = *count;
    if (cnt > 65536) cnt = 65536;
    for (int ii = blockIdx.x * 4 + w; ii < cnt; ii += 8192) {
        int n = list[ii];
        const float* zp = z + (size_t)(n >> 12) * CHW_ + (n & 4095);
#pragma unroll
        for (int j = 0; j < 4; j++)
            zd[w][l * 4 + j] = (double)zp[(size_t)(l * 4 + j) * HW_];
        asm volatile("s_waitcnt lgkmcnt(0)" ::: "memory");
        double acc[16];
#pragma unroll
        for (int a = 0; a < 16; a++) acc[a] = 0.0;
        for (int c = 0; c < 256; c++) {
            double zc = zd[w][c];
            const float* cp = cbT + (size_t)c * K_ + l * 4;
#pragma unroll
            for (int it = 0; it < 4; it++) {
                float4 cv = *(const float4*)(cp + it * 256);
                acc[it * 4 + 0] += zc * (double)cv.x;
                acc[it * 4 + 1] += zc * (double)cv.y;
                acc[it * 4 + 2] += zc * (double)cv.z;
                acc[it * 4 + 3] += zc * (double)cv.w;
            }
        }
        float szv = sz[n];
        float best = FLT_BIG; int bidx = K_;
#pragma unroll
        for (int it = 0; it < 4; it++)
#pragma unroll
            for (int s = 0; s < 4; s++) {
                int k = it * 256 + l * 4 + s;
                float dotf = (float)acc[it * 4 + s];
                float dq = (szv + sc[k]) - 2.0f * dotf;
                if (dq < best || (dq == best && k < bidx)) { best = dq; bidx = k; }
            }
#pragma unroll
        for (int off = 32; off > 0; off >>= 1) {
            float ob = __shfl_xor(best, off, 64);
            int   oj = __shfl_xor(bidx, off, 64);
            if (ob < best || (ob == best && oj < bidx)) { best = ob; bidx = oj; }
        }
        if (l == 0) { fidx[n] = bidx; out_idx[n] = (float)bidx; }
        asm volatile("s_waitcnt lgkmcnt(0)" ::: "memory");
    }
}

// ---------------------------------------------------------------------------
// Gather zq -> NCHW output + loss partials (float4 version, PASSED r8)
// ---------------------------------------------------------------------------
__global__ void output_kernel(const float* __restrict__ z, const float* __restrict__ cb,
                              const int* __restrict__ fidx,
                              float* __restrict__ out0, double* __restrict__ partials) {
    __shared__ int sidx[64];
    __shared__ double red[256];
    int t = threadIdx.x;
    int blk = blockIdx.x;
    int n0 = blk * 64;
    if (t < 64) sidx[t] = fidx[n0 + t];
    __syncthreads();
    int batch = n0 >> 12, s0 = n0 & 4095;
    const float* zbase = z + (size_t)batch * CHW_ + s0;
    float* obase = out0 + (size_t)batch * CHW_ + s0;
    int ig = (t & 15) * 4;
    int cg = (t >> 4) * 4;
    const float* r0 = cb + (size_t)sidx[ig + 0] * C_;
    const float* r1 = cb + (size_t)sidx[ig + 1] * C_;
    const float* r2 = cb + (size_t)sidx[ig + 2] * C_;
    const float* r3 = cb + (size_t)sidx[ig + 3] * C_;
    double sum = 0.0;
#pragma unroll
    for (int pass = 0; pass < 4; pass++) {
        int c0 = pass * 64 + cg;
        float4 q0 = *(const float4*)(r0 + c0);
        float4 q1 = *(const float4*)(r1 + c0);
        float4 q2 = *(const float4*)(r2 + c0);
        float4 q3 = *(const float4*)(r3 + c0);
        float a0[4] = { q0.x, q0.y, q0.z, q0.w };
        float a1[4] = { q1.x, q1.y, q1.z, q1.w };
        float a2[4] = { q2.x, q2.y, q2.z, q2.w };
        float a3[4] = { q3.x, q3.y, q3.z, q3.w };
#pragma unroll
        for (int j = 0; j < 4; j++) {
            size_t off = (size_t)(c0 + j) * HW_ + ig;
            float4 zv = *(const float4*)(zbase + off);
            float4 qq;
            qq.x = a0[j]; qq.y = a1[j]; qq.z = a2[j]; qq.w = a3[j];
            *(float4*)(obase + off) = qq;
            float d0 = qq.x - zv.x, d1 = qq.y - zv.y;
            float d2 = qq.z - zv.z, d3 = qq.w - zv.w;
            sum += (double)d0 * (double)d0;
            sum += (double)d1 * (double)d1;
            sum += (double)d2 * (double)d2;
            sum += (double)d3 * (double)d3;
        }
    }
    red[t] = sum;
    __syncthreads();
    for (int s = 128; s > 0; s >>= 1) {
        if (t < s) red[t] += red[t + s];
        __syncthreads();
    }
    if (t == 0) partials[blk] = red[0];
}

__global__ void loss_kernel(const double* __restrict__ partials, float* __restrict__ out_loss) {
    __shared__ double red[256];
    int t = threadIdx.x;
    double s = 0.0;
    for (int r = t; r < 1024; r += 256) s += partials[r];
    red[t] = s;
    __syncthreads();
    for (int k = 128; k > 0; k >>= 1) {
        if (t < k) red[t] += red[t + k];
        __syncthreads();
    }
    if (t == 0) *out_loss = (float)(0.75 * red[0] / 16777216.0);
}

// ---------------------------------------------------------------------------
extern "C" void kernel_launch(void* const* d_in, const int* in_sizes, int n_in,
                              void* d_out, int out_size, void* d_ws, size_t ws_size,
                              hipStream_t stream) {
    const float* z  = (const float*)d_in[0];
    const float* cb = (const float*)d_in[1];

    float* out0     = (float*)d_out;
    float* out_idx  = out0 + (size_t)16777216;
    float* out_loss = out0 + (size_t)16842752;

    char* w = (char*)d_ws;
    double* partials = (double*)w;                       //       0 .. 8192
    float*  sc   = (float*)(w + 8192);                   //    8192 .. 12288
    float*  sz   = (float*)(w + 12288);                  //   12288 .. 274432
    int*    fidx = (int*)  (w + 274432);                 //  274432 .. 536576 (256 KB)
    int*    count= (int*)  (w + 536576);                 //  536576 .. 536580
    int*    list = (int*)  (w + 536832);                 //  536832 .. 798976 (256 KB)
    unsigned short* cbh = (unsigned short*)(w + 798976); //  798976 .. 1323264 (512 KB)
    float*  cbT  = (float*)(w + 1323264);                // 1323264 .. 2371840 (1 MB)
    float*  rp   = (float*)(w + 2371840);                // 2371840 .. 6566144 (4 MB)

    hipMemsetAsync(count, 0, 4, stream);
    pre_kernel   <<<5188, 256, 0, stream>>>(z, cb, rp, cbh, cbT, sc);
    score_kernel <<<1024, 256, 0, stream>>>(z, cbh, sc, rp, fidx, out_idx, list, count, sz);
    refine_kernel<<<2048, 256, 0, stream>>>(z, cbT, sz, sc, list, count, fidx, out_idx);
    output_kernel<<<1024, 256, 0, stream>>>(z, cb, fidx, out0, partials);
    loss_kernel  <<<1,    256, 0, stream>>>(partials, out_loss);
}